// Round 8
// baseline (200.346 us; speedup 1.0000x reference)
//
#include <hip/hip_runtime.h>
#include <hip/hip_bf16.h>

#define D_MODEL 1024
#define NHEADS  16
#define HD      64
#define BATCH   2
#define SEQ     2048
#define NTOK    (BATCH * SEQ)   // 4096

typedef __attribute__((ext_vector_type(8))) short bf16x8;
typedef __attribute__((ext_vector_type(4))) float f32x4;

#if __has_builtin(__builtin_amdgcn_exp2f)
#define EXP2F(x) __builtin_amdgcn_exp2f(x)   // raw v_exp_f32
#else
#define EXP2F(x) exp2f(x)
#endif

static __device__ __forceinline__ short f2bf(float f) {
    union { float f; unsigned u; } x; x.f = f;
    unsigned r = (x.u + 0x7fffu + ((x.u >> 16) & 1u)) >> 16;  // RNE
    return (short)r;
}

// pack two fp32 -> bf16 pair (RNE), as one dword
static __device__ __forceinline__ unsigned pk_bf16(float a, float b) {
    __hip_bfloat162 h2 = __float22bfloat162_rn(make_float2(a, b));
    union { __hip_bfloat162 h; unsigned u; } c; c.h = h2;
    return c.u;
}

// async global->LDS, 16B per lane; LDS dest = wave-uniform base + lane*16
static __device__ __forceinline__ void gl_lds16(const short* g, short* l) {
    __builtin_amdgcn_global_load_lds((const __attribute__((address_space(1))) void*)g,
                                     (__attribute__((address_space(3))) void*)l,
                                     16, 0, 0);
}

// ---------------------------------------------------------------------------
// Fused prep: cast x -> bf16 (blocks 0..4095), transpose+cast Wqkv with
// softmax scale folded into Q-columns (blocks 4096..7167), transpose+cast Wo
// (blocks 7168..8191). One launch instead of three.
// ---------------------------------------------------------------------------
__global__ __launch_bounds__(256) void prep_kernel(const float* __restrict__ x,
                                                   short* __restrict__ x_bf,
                                                   const float* __restrict__ Wqkv,
                                                   short* __restrict__ WqkvT,
                                                   const float* __restrict__ Wo,
                                                   short* __restrict__ WoT,
                                                   float cexp) {
    int bid = blockIdx.x;
    int tid = threadIdx.x;

    if (bid < 4096) {
        int i = bid * 256 + tid;
        float4 v = ((const float4*)x)[i];
        short4 o;
        o.x = f2bf(v.x); o.y = f2bf(v.y); o.z = f2bf(v.z); o.w = f2bf(v.w);
        ((short4*)x_bf)[i] = o;
        return;
    }

    __shared__ float tile[32][33];
    const float* in; short* out; int R, C, slimit; float sc; int bx, by;
    if (bid < 4096 + 3072) {
        int idx = bid - 4096;
        in = Wqkv; out = WqkvT; R = D_MODEL; C = 3 * D_MODEL;
        slimit = D_MODEL; sc = cexp;
        bx = idx % 96; by = idx / 96;
    } else {
        int idx = bid - 7168;
        in = Wo; out = WoT; R = D_MODEL; C = D_MODEL;
        slimit = 0; sc = 1.0f;
        bx = idx % 32; by = idx / 32;
    }
    int bc = bx * 32, br = by * 32;
    int tx = tid & 31, ty = tid >> 5;   // 32 x 8
    #pragma unroll
    for (int i = 0; i < 32; i += 8)
        tile[ty + i][tx] = in[(long)(br + ty + i) * C + bc + tx];
    __syncthreads();
    #pragma unroll
    for (int i = 0; i < 32; i += 8) {
        int orow = bc + ty + i;
        float v = tile[tx][ty + i];
        if (orow < slimit) v *= sc;
        out[(long)orow * R + br + tx] = f2bf(v);
    }
}

// ---------------------------------------------------------------------------
// Output-proj GEMM: 128x64 tiles (512 blocks = 2/CU). BK=64 via two
// stride-32 LDS buffers (R7: measured neutral, kept).
// ---------------------------------------------------------------------------
__global__ __launch_bounds__(256) void gemm_out(const short* __restrict__ A,
                                                const short* __restrict__ BT,
                                                float* __restrict__ C,
                                                int M, int N, int K) {
    __shared__ short As[2][128 * 32];
    __shared__ short Bs[2][64 * 32];

    int tid  = threadIdx.x;
    int lane = tid & 63;
    int w    = tid >> 6;
    int quad = lane >> 4;
    int l16  = lane & 15;

    int m_blk = blockIdx.y * 128, n_blk = blockIdx.x * 64;

    const short* Ag = A  + (long)(m_blk + w * 32 + (lane >> 2)) * K + (lane & 3) * 8;
    const short* Bg = BT + (long)(n_blk + w * 16 + (lane >> 2)) * K + (lane & 3) * 8;
    short* As0 = &As[0][(w * 32) * 32];
    short* As1 = &As[1][(w * 32) * 32];
    short* Bs0 = &Bs[0][(w * 16) * 32];
    short* Bs1 = &Bs[1][(w * 16) * 32];

    f32x4 acc[2][4] = {};

    for (int k0 = 0; k0 < K; k0 += 64) {
        __syncthreads();
        gl_lds16(Ag + k0,               As0);
        gl_lds16(Ag + 16 * K + k0,      As0 + 16 * 32);
        gl_lds16(Ag + k0 + 32,          As1);
        gl_lds16(Ag + 16 * K + k0 + 32, As1 + 16 * 32);
        gl_lds16(Bg + k0,               Bs0);
        gl_lds16(Bg + k0 + 32,          Bs1);
        __syncthreads();

        #pragma unroll
        for (int kk = 0; kk < 2; kk++) {
            bf16x8 a[2], b[4];
            #pragma unroll
            for (int i = 0; i < 2; i++)
                a[i] = *(const bf16x8*)&As[kk][(w * 32 + i * 16 + l16) * 32 + quad * 8];
            #pragma unroll
            for (int j = 0; j < 4; j++)
                b[j] = *(const bf16x8*)&Bs[kk][(j * 16 + l16) * 32 + quad * 8];
            #pragma unroll
            for (int i = 0; i < 2; i++)
                #pragma unroll
                for (int j = 0; j < 4; j++)
                    acc[i][j] = __builtin_amdgcn_mfma_f32_16x16x32_bf16(a[i], b[j], acc[i][j], 0, 0, 0);
        }
    }

    #pragma unroll
    for (int i = 0; i < 2; i++)
        #pragma unroll
        for (int j = 0; j < 4; j++)
            #pragma unroll
            for (int r = 0; r < 4; r++) {
                int row = m_blk + w * 32 + i * 16 + quad * 4 + r;
                int col = n_blk + j * 16 + l16;
                C[(long)row * N + col] = acc[i][j][r];
            }
}

// ---------------------------------------------------------------------------
// QKV GEMM with FUSED repack epilogue (R6-verified) + BK=64 + XCD n-chunk
// swizzle (R7: measured neutral, kept). Epilogue bit-identical to R6.
// ---------------------------------------------------------------------------
__global__ __launch_bounds__(256) void gemm_qkv(const short* __restrict__ A,
                                                const short* __restrict__ BT,
                                                short* __restrict__ Qb,
                                                short* __restrict__ Kt2,
                                                short* __restrict__ Vt2) {
    const int K = 1024;
    __shared__ union {
        struct { short As[2][128 * 32]; short Bs[2][128 * 32]; } g;  // 32 KB
        short Tl[4][64][72];            // wave-private 64x64 epilogue tiles (36 KB)
    } sh;

    int tid  = threadIdx.x;
    int lane = tid & 63;
    int w    = tid >> 6;
    int quad = lane >> 4;
    int l16  = lane & 15;

    // dispatch-linear id; xcd = bid%8 (round-robin heuristic), bijective remap
    int bid = blockIdx.y * 24 + blockIdx.x;
    int xcd = bid & 7;
    int pos = bid >> 3;                 // 0..95
    int nb  = xcd * 3 + (pos % 3);      // n-block 0..23 (3 per XCD)
    int mb  = pos / 3;                  // m-block 0..31

    int m_blk = mb * 128, n_blk = nb * 128;
    int mh = (w >> 1) * 64, nh = (w & 1) * 64;

    int sel = nb >> 3;                  // 0:Q 1:K 2:V (uniform per block)
    int ncol0 = n_blk - sel * 1024;

    const short* Ag = A  + (long)(m_blk + w * 32 + (lane >> 2)) * K + (lane & 3) * 8;
    const short* Bg = BT + (long)(n_blk + w * 32 + (lane >> 2)) * K + (lane & 3) * 8;
    short* As0 = &sh.g.As[0][(w * 32) * 32];
    short* As1 = &sh.g.As[1][(w * 32) * 32];
    short* Bs0 = &sh.g.Bs[0][(w * 32) * 32];
    short* Bs1 = &sh.g.Bs[1][(w * 32) * 32];

    f32x4 acc[4][4] = {};

    for (int k0 = 0; k0 < K; k0 += 64) {
        __syncthreads();
        gl_lds16(Ag + k0,               As0);
        gl_lds16(Ag + 16 * K + k0,      As0 + 16 * 32);
        gl_lds16(Ag + k0 + 32,          As1);
        gl_lds16(Ag + 16 * K + k0 + 32, As1 + 16 * 32);
        gl_lds16(Bg + k0,               Bs0);
        gl_lds16(Bg + 16 * K + k0,      Bs0 + 16 * 32);
        gl_lds16(Bg + k0 + 32,          Bs1);
        gl_lds16(Bg + 16 * K + k0 + 32, Bs1 + 16 * 32);
        __syncthreads();

        #pragma unroll
        for (int kk = 0; kk < 2; kk++) {
            bf16x8 a[4], b[4];
            #pragma unroll
            for (int i = 0; i < 4; i++)
                a[i] = *(const bf16x8*)&sh.g.As[kk][(mh + i * 16 + l16) * 32 + quad * 8];
            #pragma unroll
            for (int j = 0; j < 4; j++)
                b[j] = *(const bf16x8*)&sh.g.Bs[kk][(nh + j * 16 + l16) * 32 + quad * 8];
            #pragma unroll
            for (int i = 0; i < 4; i++)
                #pragma unroll
                for (int j = 0; j < 4; j++)
                    acc[i][j] = __builtin_amdgcn_mfma_f32_16x16x32_bf16(a[i], b[j], acc[i][j], 0, 0, 0);
        }
    }

    // all waves done with As/Bs before the union is reused
    __syncthreads();

    // stage this wave's 64x64 bf16 tile into its private LDS buffer
    #pragma unroll
    for (int i = 0; i < 4; i++)
        #pragma unroll
        for (int j = 0; j < 4; j++)
            #pragma unroll
            for (int r = 0; r < 4; r++)
                sh.Tl[w][i * 16 + quad * 4 + r][j * 16 + l16] = f2bf(acc[i][j][r]);

    int R0q = m_blk + mh;                      // global token-row base of subtile
    if (sel == 0) {
        long qbase = (long)R0q * 1024 + (ncol0 + nh);
        #pragma unroll
        for (int ch = 0; ch < 8; ch++) {
            int row  = ch * 8 + (lane >> 3);
            int col0 = (lane & 7) * 8;
            *(bf16x8*)(Qb + qbase + (long)row * 1024 + col0) =
                *(const bf16x8*)&sh.Tl[w][row][col0];
        }
    } else {
        int b2 = R0q >> 11;                    // batch
        int t  = (R0q & 2047) >> 6;            // 64-key tile within sequence
        int h  = (ncol0 + nh) >> 6;            // head
        long obase = (long)(b2 * 16 + h) * (SEQ * 64) + (long)t * 4096;
        short* outT = (sel == 1) ? Kt2 : Vt2;
        if (sel == 1) {
            #pragma unroll
            for (int ch = 0; ch < 8; ch++) {
                int o = lane * 64 + ch * 8;
                int u = o >> 9, qd = (o >> 7) & 3, l = (o >> 3) & 15;
                int row = (u >> 2) * 32 + ((u >> 1) & 1) * 16 + l;
                int col = (u & 1) * 32 + qd * 8;
                *(bf16x8*)(outT + obase + o) = *(const bf16x8*)&sh.Tl[w][row][col];
            }
        } else {
            #pragma unroll
            for (int ch = 0; ch < 8; ch++) {
                int o = lane * 64 + ch * 8;
                int c = o >> 11, j2 = (o >> 9) & 3, qd = (o >> 7) & 3, l = (o >> 3) & 15;
                int hd = j2 * 16 + l;
                bf16x8 ov;
                #pragma unroll
                for (int jj = 0; jj < 8; jj++) {
                    int s = c * 32 + qd * 8 + jj;
                    int key = (s >> 2) + ((s & 3) << 4);
                    ov[jj] = sh.Tl[w][key][hd];
                }
                *(bf16x8*)(outT + obase + o) = ov;
            }
        }
    }
}

// ---------------------------------------------------------------------------
// Flash attention, round-8 restructure: m=1 (16 q-rows/wave), NO key split.
//   Block = 64 q-rows (wave w owns rows w*16..w*16+15); all 4 waves sweep
//   all 32 key-tiles together -> identical kf/vf loads are L1-MSHR-merged
//   (R4-verified mechanism) while grid stays 1024 = 4 blocks/CU (R4's
//   occupancy mistake avoided).
//   m=1 frees ~36 VGPRs vs the m=2 body (O[1][4], z[1][4], aQ[2], Lacc[1])
//   -> kf cross-iteration prefetch FITS the 128-reg cap (R3's mechanism
//   without R3's spill): kf for t+1 issued right after vf, in-place; its
//   vmcnt wait lands after ~600cy of exp/pack/PV. Tail prefetch (t=31)
//   reads 8KB past this bh's K = next region (valid workspace, harmless),
//   keeping the loop branchless.
//   No merge phase, no barriers at all: each wave rescales and stores its
//   own 16 rows. 32 short iterations interleave finer across the 4
//   waves/SIMD than 16 long ones.
//   Spill tripwires: VGPR_Count > ~110 or WRITE_SIZE >> 13 MB.
// ---------------------------------------------------------------------------
__global__ __launch_bounds__(256, 4) void flash_attn(const short* __restrict__ Qb,
                                                     const short* __restrict__ Kt2,
                                                     const short* __restrict__ Vt2,
                                                     short* __restrict__ y) {
    int tid  = threadIdx.x;
    int lane = tid & 63;
    int w    = tid >> 6;
    int quad = lane >> 4;
    int l16  = lane & 15;

    int bh = blockIdx.y;
    int b  = bh >> 4;
    int h  = bh & 15;
    int qw = blockIdx.x * 64 + w * 16;   // wave-private 16 q-rows

    __shared__ short Ps[4][16 * 72];     // wave-private P tiles (9216 B)
    short* PsW = &Ps[w][0];

    const short* Qrow = Qb + ((long)b * SEQ + qw + l16) * 1024 + h * 64;
    bf16x8 aQ[2];
    #pragma unroll
    for (int c = 0; c < 2; c++)
        aQ[c] = *(const bf16x8*)(Qrow + c * 32 + quad * 8);

    const short* Ktb = Kt2 + (long)bh * (SEQ * 64);
    const short* Vtb = Vt2 + (long)bh * (SEQ * 64);

    f32x4 O[4] = {};
    f32x4 Lacc = {};
    bf16x8 ones;
    #pragma unroll
    for (int i = 0; i < 8; i++) ones[i] = (short)0x3F80;   // bf16 1.0

    // prologue: K frags for t=0
    bf16x8 kf[8];
    #pragma unroll
    for (int u = 0; u < 8; u++) kf[u] = *(const bf16x8*)(Ktb + u * 512 + lane * 8);

    for (int t = 0; t < 32; t++) {
        const short* Vt  = Vtb + t * 4096;
        const short* Ktn = Ktb + (t + 1) * 4096;

        // S = Q K^T: 4 key-cols, 2 chained d-chunks each (kf prefetched)
        f32x4 z[4];
        #pragma unroll
        for (int kc = 0; kc < 4; kc++) {
            f32x4 zz = {};
            zz = __builtin_amdgcn_mfma_f32_16x16x32_bf16(aQ[0], kf[2 * kc],     zz, 0, 0, 0);
            z[kc] = __builtin_amdgcn_mfma_f32_16x16x32_bf16(aQ[1], kf[2 * kc + 1], zz, 0, 0, 0);
        }

        // V frags for t (consumed after exp/pack), then kf prefetch for t+1
        // (kf dead after the S-MFMAs above; in-place reload, no extra regs)
        bf16x8 vf[8];
        #pragma unroll
        for (int u = 0; u < 8; u++) vf[u] = *(const bf16x8*)(Vt + u * 512 + lane * 8);
        #pragma unroll
        for (int u = 0; u < 8; u++) kf[u] = *(const bf16x8*)(Ktn + u * 512 + lane * 8);

        // p = exp2(z); packed bf16 cvt; one b64 LDS write per r
        #pragma unroll
        for (int r = 0; r < 4; r++) {
            unsigned d0 = pk_bf16(EXP2F(z[0][r]), EXP2F(z[1][r]));
            unsigned d1 = pk_bf16(EXP2F(z[2][r]), EXP2F(z[3][r]));
            unsigned long long dd = ((unsigned long long)d1 << 32) | d0;
            *(unsigned long long*)((unsigned*)PsW + (quad * 4 + r) * 36 + 2 * l16) = dd;
        }

        // PV + row-sum (ones-column MFMA)
        #pragma unroll
        for (int c = 0; c < 2; c++) {
            bf16x8 aP = *(const bf16x8*)(PsW + l16 * 72 + c * 32 + quad * 8);
            Lacc = __builtin_amdgcn_mfma_f32_16x16x32_bf16(aP, ones, Lacc, 0, 0, 0);
            #pragma unroll
            for (int j = 0; j < 4; j++)
                O[j] = __builtin_amdgcn_mfma_f32_16x16x32_bf16(aP, vf[c * 4 + j], O[j], 0, 0, 0);
        }
    }

    // direct epilogue: each wave owns its 16 rows — no merge, no barrier
    f32x4 rl;
    #pragma unroll
    for (int r = 0; r < 4; r++) rl[r] = 1.0f / Lacc[r];
    #pragma unroll
    for (int j = 0; j < 4; j++)
        #pragma unroll
        for (int r = 0; r < 4; r++) {
            int row = qw + quad * 4 + r;
            y[((long)b * SEQ + row) * D_MODEL + h * HD + j * 16 + l16] =
                f2bf(O[j][r] * rl[r]);
        }
}

// ---------------------------------------------------------------------------
// Workspace (48 MB): Qb@0, yb@8M, Kt2@24M, Vt2@32M, WqkvT@40M, WoT@46M.
// x_bf scratched in d_out. repack_kv fused into gemm_qkv.
// ---------------------------------------------------------------------------
extern "C" void kernel_launch(void* const* d_in, const int* in_sizes, int n_in,
                              void* d_out, int out_size, void* d_ws, size_t ws_size,
                              hipStream_t stream) {
    const float* x    = (const float*)d_in[0];
    const float* Wqkv = (const float*)d_in[1];
    const float* Wo   = (const float*)d_in[2];

    char* ws = (char*)d_ws;
    short* Qb    = (short*)(ws);
    short* Kt2   = (short*)(ws + 25165824);
    short* Vt2   = (short*)(ws + 33554432);
    short* WqkvT = (short*)(ws + 41943040);
    short* WoT   = (short*)(ws + 48234496);
    short* x_bf  = (short*)d_out;            // scratch in d_out (16 MB fp32)
    short* yb    = (short*)(ws + 8388608);

    const float cexp = 0.125f * 1.4426950408889634f;  // 1/sqrt(64) * log2(e)

    prep_kernel<<<8192, 256, 0, stream>>>(x, x_bf, Wqkv, WqkvT, Wo, WoT, cexp);

    gemm_qkv<<<dim3(3 * D_MODEL / 128, NTOK / 128), 256, 0, stream>>>(
        x_bf, WqkvT, Qb, Kt2, Vt2);

    flash_attn<<<dim3(SEQ / 64, BATCH * NHEADS), 256, 0, stream>>>(Qb, Kt2, Vt2, yb);

    gemm_out<<<dim3(D_MODEL / 64, NTOK / 128), 256, 0, stream>>>(
        yb, WoT, (float*)d_out, NTOK, D_MODEL, D_MODEL);
}

// Round 9
// 193.126 us; speedup vs baseline: 1.0374x; 1.0374x over previous
//
#include <hip/hip_runtime.h>
#include <hip/hip_bf16.h>

#define D_MODEL 1024
#define NHEADS  16
#define HD      64
#define BATCH   2
#define SEQ     2048
#define NTOK    (BATCH * SEQ)   // 4096

typedef __attribute__((ext_vector_type(8))) short bf16x8;
typedef __attribute__((ext_vector_type(4))) float f32x4;

#if __has_builtin(__builtin_amdgcn_exp2f)
#define EXP2F(x) __builtin_amdgcn_exp2f(x)   // raw v_exp_f32
#else
#define EXP2F(x) exp2f(x)
#endif

static __device__ __forceinline__ short f2bf(float f) {
    union { float f; unsigned u; } x; x.f = f;
    unsigned r = (x.u + 0x7fffu + ((x.u >> 16) & 1u)) >> 16;  // RNE
    return (short)r;
}

// pack two fp32 -> bf16 pair (RNE), as one dword
static __device__ __forceinline__ unsigned pk_bf16(float a, float b) {
    __hip_bfloat162 h2 = __float22bfloat162_rn(make_float2(a, b));
    union { __hip_bfloat162 h; unsigned u; } c; c.h = h2;
    return c.u;
}

// async global->LDS, 16B per lane; LDS dest = wave-uniform base + lane*16
static __device__ __forceinline__ void gl_lds16(const short* g, short* l) {
    __builtin_amdgcn_global_load_lds((const __attribute__((address_space(1))) void*)g,
                                     (__attribute__((address_space(3))) void*)l,
                                     16, 0, 0);
}

// ---------------------------------------------------------------------------
// Fused prep: cast x -> bf16 (blocks 0..4095), transpose+cast Wqkv with
// softmax scale folded into Q-columns (blocks 4096..7167), transpose+cast Wo
// (blocks 7168..8191). One launch instead of three.
// ---------------------------------------------------------------------------
__global__ __launch_bounds__(256) void prep_kernel(const float* __restrict__ x,
                                                   short* __restrict__ x_bf,
                                                   const float* __restrict__ Wqkv,
                                                   short* __restrict__ WqkvT,
                                                   const float* __restrict__ Wo,
                                                   short* __restrict__ WoT,
                                                   float cexp) {
    int bid = blockIdx.x;
    int tid = threadIdx.x;

    if (bid < 4096) {
        int i = bid * 256 + tid;
        float4 v = ((const float4*)x)[i];
        short4 o;
        o.x = f2bf(v.x); o.y = f2bf(v.y); o.z = f2bf(v.z); o.w = f2bf(v.w);
        ((short4*)x_bf)[i] = o;
        return;
    }

    __shared__ float tile[32][33];
    const float* in; short* out; int R, C, slimit; float sc; int bx, by;
    if (bid < 4096 + 3072) {
        int idx = bid - 4096;
        in = Wqkv; out = WqkvT; R = D_MODEL; C = 3 * D_MODEL;
        slimit = D_MODEL; sc = cexp;
        bx = idx % 96; by = idx / 96;
    } else {
        int idx = bid - 7168;
        in = Wo; out = WoT; R = D_MODEL; C = D_MODEL;
        slimit = 0; sc = 1.0f;
        bx = idx % 32; by = idx / 32;
    }
    int bc = bx * 32, br = by * 32;
    int tx = tid & 31, ty = tid >> 5;   // 32 x 8
    #pragma unroll
    for (int i = 0; i < 32; i += 8)
        tile[ty + i][tx] = in[(long)(br + ty + i) * C + bc + tx];
    __syncthreads();
    #pragma unroll
    for (int i = 0; i < 32; i += 8) {
        int orow = bc + ty + i;
        float v = tile[tx][ty + i];
        if (orow < slimit) v *= sc;
        out[(long)orow * R + br + tx] = f2bf(v);
    }
}

// ---------------------------------------------------------------------------
// Output-proj GEMM, round-9: 128x128 tiles, 512 threads / 8 waves
// (wave = 32x64 out, 2x4 acc -- same per-wave register shape as the old
// 128x64 version, zero spill risk). 256 blocks = 1/CU, 2 waves/SIMD (same
// TLP as before). MFMA:staging per block rises 64:6 -> 128:8; A re-read
// halves (8 n-blocks instead of 16). BK=64 staging as in gemm_qkv.
// ---------------------------------------------------------------------------
__global__ __launch_bounds__(512) void gemm_out(const short* __restrict__ A,
                                                const short* __restrict__ BT,
                                                float* __restrict__ C,
                                                int M, int N, int K) {
    __shared__ short As[2][128 * 32];
    __shared__ short Bs[2][128 * 32];

    int tid  = threadIdx.x;
    int lane = tid & 63;
    int w    = tid >> 6;        // 0..7
    int quad = lane >> 4;
    int l16  = lane & 15;
    int wr   = w & 3;           // row-quarter: 32 rows
    int wc   = w >> 2;          // col-half: 64 cols

    int m_blk = blockIdx.y * 128, n_blk = blockIdx.x * 128;

    // staging: 8 waves x 16 rows each cover 128 rows per buffer
    const short* Ag = A  + (long)(m_blk + w * 16 + (lane >> 2)) * K + (lane & 3) * 8;
    const short* Bg = BT + (long)(n_blk + w * 16 + (lane >> 2)) * K + (lane & 3) * 8;
    short* As0 = &As[0][(w * 16) * 32];
    short* As1 = &As[1][(w * 16) * 32];
    short* Bs0 = &Bs[0][(w * 16) * 32];
    short* Bs1 = &Bs[1][(w * 16) * 32];

    f32x4 acc[2][4] = {};

    for (int k0 = 0; k0 < K; k0 += 64) {
        __syncthreads();
        gl_lds16(Ag + k0,      As0);
        gl_lds16(Ag + k0 + 32, As1);
        gl_lds16(Bg + k0,      Bs0);
        gl_lds16(Bg + k0 + 32, Bs1);
        __syncthreads();

        #pragma unroll
        for (int kk = 0; kk < 2; kk++) {
            bf16x8 a[2], b[4];
            #pragma unroll
            for (int i = 0; i < 2; i++)
                a[i] = *(const bf16x8*)&As[kk][(wr * 32 + i * 16 + l16) * 32 + quad * 8];
            #pragma unroll
            for (int j = 0; j < 4; j++)
                b[j] = *(const bf16x8*)&Bs[kk][(wc * 64 + j * 16 + l16) * 32 + quad * 8];
            #pragma unroll
            for (int i = 0; i < 2; i++)
                #pragma unroll
                for (int j = 0; j < 4; j++)
                    acc[i][j] = __builtin_amdgcn_mfma_f32_16x16x32_bf16(a[i], b[j], acc[i][j], 0, 0, 0);
        }
    }

    #pragma unroll
    for (int i = 0; i < 2; i++)
        #pragma unroll
        for (int j = 0; j < 4; j++)
            #pragma unroll
            for (int r = 0; r < 4; r++) {
                int row = m_blk + wr * 32 + i * 16 + quad * 4 + r;
                int col = n_blk + wc * 64 + j * 16 + l16;
                C[(long)row * N + col] = acc[i][j][r];
            }
}

// ---------------------------------------------------------------------------
// QKV GEMM with FUSED repack epilogue (R6-verified) + BK=64 + XCD n-chunk
// swizzle (R7: measured neutral, kept). Epilogue bit-identical to R6.
// ---------------------------------------------------------------------------
__global__ __launch_bounds__(256) void gemm_qkv(const short* __restrict__ A,
                                                const short* __restrict__ BT,
                                                short* __restrict__ Qb,
                                                short* __restrict__ Kt2,
                                                short* __restrict__ Vt2) {
    const int K = 1024;
    __shared__ union {
        struct { short As[2][128 * 32]; short Bs[2][128 * 32]; } g;  // 32 KB
        short Tl[4][64][72];            // wave-private 64x64 epilogue tiles (36 KB)
    } sh;

    int tid  = threadIdx.x;
    int lane = tid & 63;
    int w    = tid >> 6;
    int quad = lane >> 4;
    int l16  = lane & 15;

    // dispatch-linear id; xcd = bid%8 (round-robin heuristic), bijective remap
    int bid = blockIdx.y * 24 + blockIdx.x;
    int xcd = bid & 7;
    int pos = bid >> 3;                 // 0..95
    int nb  = xcd * 3 + (pos % 3);      // n-block 0..23 (3 per XCD)
    int mb  = pos / 3;                  // m-block 0..31

    int m_blk = mb * 128, n_blk = nb * 128;
    int mh = (w >> 1) * 64, nh = (w & 1) * 64;

    int sel = nb >> 3;                  // 0:Q 1:K 2:V (uniform per block)
    int ncol0 = n_blk - sel * 1024;

    const short* Ag = A  + (long)(m_blk + w * 32 + (lane >> 2)) * K + (lane & 3) * 8;
    const short* Bg = BT + (long)(n_blk + w * 32 + (lane >> 2)) * K + (lane & 3) * 8;
    short* As0 = &sh.g.As[0][(w * 32) * 32];
    short* As1 = &sh.g.As[1][(w * 32) * 32];
    short* Bs0 = &sh.g.Bs[0][(w * 32) * 32];
    short* Bs1 = &sh.g.Bs[1][(w * 32) * 32];

    f32x4 acc[4][4] = {};

    for (int k0 = 0; k0 < K; k0 += 64) {
        __syncthreads();
        gl_lds16(Ag + k0,               As0);
        gl_lds16(Ag + 16 * K + k0,      As0 + 16 * 32);
        gl_lds16(Ag + k0 + 32,          As1);
        gl_lds16(Ag + 16 * K + k0 + 32, As1 + 16 * 32);
        gl_lds16(Bg + k0,               Bs0);
        gl_lds16(Bg + 16 * K + k0,      Bs0 + 16 * 32);
        gl_lds16(Bg + k0 + 32,          Bs1);
        gl_lds16(Bg + 16 * K + k0 + 32, Bs1 + 16 * 32);
        __syncthreads();

        #pragma unroll
        for (int kk = 0; kk < 2; kk++) {
            bf16x8 a[4], b[4];
            #pragma unroll
            for (int i = 0; i < 4; i++)
                a[i] = *(const bf16x8*)&sh.g.As[kk][(mh + i * 16 + l16) * 32 + quad * 8];
            #pragma unroll
            for (int j = 0; j < 4; j++)
                b[j] = *(const bf16x8*)&sh.g.Bs[kk][(nh + j * 16 + l16) * 32 + quad * 8];
            #pragma unroll
            for (int i = 0; i < 4; i++)
                #pragma unroll
                for (int j = 0; j < 4; j++)
                    acc[i][j] = __builtin_amdgcn_mfma_f32_16x16x32_bf16(a[i], b[j], acc[i][j], 0, 0, 0);
        }
    }

    // all waves done with As/Bs before the union is reused
    __syncthreads();

    // stage this wave's 64x64 bf16 tile into its private LDS buffer
    #pragma unroll
    for (int i = 0; i < 4; i++)
        #pragma unroll
        for (int j = 0; j < 4; j++)
            #pragma unroll
            for (int r = 0; r < 4; r++)
                sh.Tl[w][i * 16 + quad * 4 + r][j * 16 + l16] = f2bf(acc[i][j][r]);

    int R0q = m_blk + mh;                      // global token-row base of subtile
    if (sel == 0) {
        long qbase = (long)R0q * 1024 + (ncol0 + nh);
        #pragma unroll
        for (int ch = 0; ch < 8; ch++) {
            int row  = ch * 8 + (lane >> 3);
            int col0 = (lane & 7) * 8;
            *(bf16x8*)(Qb + qbase + (long)row * 1024 + col0) =
                *(const bf16x8*)&sh.Tl[w][row][col0];
        }
    } else {
        int b2 = R0q >> 11;                    // batch
        int t  = (R0q & 2047) >> 6;            // 64-key tile within sequence
        int h  = (ncol0 + nh) >> 6;            // head
        long obase = (long)(b2 * 16 + h) * (SEQ * 64) + (long)t * 4096;
        short* outT = (sel == 1) ? Kt2 : Vt2;
        if (sel == 1) {
            #pragma unroll
            for (int ch = 0; ch < 8; ch++) {
                int o = lane * 64 + ch * 8;
                int u = o >> 9, qd = (o >> 7) & 3, l = (o >> 3) & 15;
                int row = (u >> 2) * 32 + ((u >> 1) & 1) * 16 + l;
                int col = (u & 1) * 32 + qd * 8;
                *(bf16x8*)(outT + obase + o) = *(const bf16x8*)&sh.Tl[w][row][col];
            }
        } else {
            #pragma unroll
            for (int ch = 0; ch < 8; ch++) {
                int o = lane * 64 + ch * 8;
                int c = o >> 11, j2 = (o >> 9) & 3, qd = (o >> 7) & 3, l = (o >> 3) & 15;
                int hd = j2 * 16 + l;
                bf16x8 ov;
                #pragma unroll
                for (int jj = 0; jj < 8; jj++) {
                    int s = c * 32 + qd * 8 + jj;
                    int key = (s >> 2) + ((s & 3) << 4);
                    ov[jj] = sh.Tl[w][key][hd];
                }
                *(bf16x8*)(outT + obase + o) = ov;
            }
        }
    }
}

// ---------------------------------------------------------------------------
// Flash attention: byte-exact round-0 version (best measured: 55.5-57.2 us).
// Fragment-direct, 32 q/wave, K-split x2; grid (SEQ/64, BH) = 1024 blocks.
// Closed ledger (R1-R8): occupancy register-capped at 4 waves/SIMD; dur
// invariant to FETCH 14-71 MB / occupancy 17-33%; m=1 halves per-wave
// arithmetic intensity (80 us); prefetch spills; swizzle+setprio cost ~3 us.
// This geometry is the local optimum of the structure.
// ---------------------------------------------------------------------------
__global__ __launch_bounds__(256, 4) void flash_attn(const short* __restrict__ Qb,
                                                     const short* __restrict__ Kt2,
                                                     const short* __restrict__ Vt2,
                                                     short* __restrict__ y) {
    int tid  = threadIdx.x;
    int lane = tid & 63;
    int w    = tid >> 6;
    int quad = lane >> 4;
    int l16  = lane & 15;
    int qsel = w & 1;
    int ksel = w >> 1;

    int bh = blockIdx.y;
    int b  = bh >> 4;
    int h  = bh & 15;
    int qw = blockIdx.x * 64 + qsel * 32;

    __shared__ union {
        short Ps[4][32 * 72];   // wave-private P tiles (18432 B)
        float Mg[2][64][41];    // merge buffers (20992 B), used after loop
    } sh;
    short* PsW = &sh.Ps[w][0];

    const short* Qrow = Qb + ((long)b * SEQ + qw + l16) * 1024 + h * 64;
    bf16x8 aQ[2][2];
    #pragma unroll
    for (int m = 0; m < 2; m++)
        #pragma unroll
        for (int c = 0; c < 2; c++)
            aQ[m][c] = *(const bf16x8*)(Qrow + (long)(m * 16) * 1024 + c * 32 + quad * 8);

    const short* Ktb = Kt2 + (long)bh * (SEQ * 64) + (long)ksel * 16 * 4096;
    const short* Vtb = Vt2 + (long)bh * (SEQ * 64) + (long)ksel * 16 * 4096;

    f32x4 O[2][4] = {};
    f32x4 Lacc[2] = {};
    bf16x8 ones;
    #pragma unroll
    for (int i = 0; i < 8; i++) ones[i] = (short)0x3F80;   // bf16 1.0

    for (int t = 0; t < 16; t++) {
        const short* Kt = Ktb + t * 4096;
        const short* Vt = Vtb + t * 4096;

        // K fragment loads (coalesced 1KB dwordx4)
        bf16x8 kf[8];
        #pragma unroll
        for (int u = 0; u < 8; u++) kf[u] = *(const bf16x8*)(Kt + u * 512 + lane * 8);

        // S = Q K^T: 2 m-frags x 4 key-cols, 2 chained d-chunks each
        f32x4 z[2][4];
        #pragma unroll
        for (int m = 0; m < 2; m++)
            #pragma unroll
            for (int kc = 0; kc < 4; kc++) {
                f32x4 zz = {};
                zz = __builtin_amdgcn_mfma_f32_16x16x32_bf16(aQ[m][0], kf[2 * kc],     zz, 0, 0, 0);
                z[m][kc] = __builtin_amdgcn_mfma_f32_16x16x32_bf16(aQ[m][1], kf[2 * kc + 1], zz, 0, 0, 0);
            }

        // V fragment loads — issued now, consumed after exp/pack (latency hidden)
        bf16x8 vf[8];
        #pragma unroll
        for (int u = 0; u < 8; u++) vf[u] = *(const bf16x8*)(Vt + u * 512 + lane * 8);

        // p = exp2(z) (raw v_exp_f32); packed bf16 cvt; one b64 write per (m,r)
        #pragma unroll
        for (int m = 0; m < 2; m++)
            #pragma unroll
            for (int r = 0; r < 4; r++) {
                unsigned d0 = pk_bf16(EXP2F(z[m][0][r]), EXP2F(z[m][1][r]));
                unsigned d1 = pk_bf16(EXP2F(z[m][2][r]), EXP2F(z[m][3][r]));
                unsigned long long dd = ((unsigned long long)d1 << 32) | d0;
                *(unsigned long long*)((unsigned*)PsW + (m * 16 + quad * 4 + r) * 36 + 2 * l16) = dd;
            }

        // PV + row-sum (ones-column MFMA); bV shared across both m-frags
        #pragma unroll
        for (int c = 0; c < 2; c++) {
            bf16x8 aP0 = *(const bf16x8*)(PsW + (l16) * 72      + c * 32 + quad * 8);
            bf16x8 aP1 = *(const bf16x8*)(PsW + (16 + l16) * 72 + c * 32 + quad * 8);
            Lacc[0] = __builtin_amdgcn_mfma_f32_16x16x32_bf16(aP0, ones, Lacc[0], 0, 0, 0);
            Lacc[1] = __builtin_amdgcn_mfma_f32_16x16x32_bf16(aP1, ones, Lacc[1], 0, 0, 0);
            #pragma unroll
            for (int j = 0; j < 4; j++) {
                O[0][j] = __builtin_amdgcn_mfma_f32_16x16x32_bf16(aP0, vf[c * 4 + j], O[0][j], 0, 0, 0);
                O[1][j] = __builtin_amdgcn_mfma_f32_16x16x32_bf16(aP1, vf[c * 4 + j], O[1][j], 0, 0, 0);
            }
        }
    }

    // additive merge of key-split partners (w, w+2) — Ps is dead, reuse as Mg
    __syncthreads();
    if (ksel) {
        float* mg = &sh.Mg[qsel][lane][0];
        #pragma unroll
        for (int m = 0; m < 2; m++)
            #pragma unroll
            for (int j = 0; j < 4; j++)
                #pragma unroll
                for (int r = 0; r < 4; r++)
                    mg[m * 16 + j * 4 + r] = O[m][j][r];
        #pragma unroll
        for (int m = 0; m < 2; m++)
            #pragma unroll
            for (int r = 0; r < 4; r++)
                mg[32 + m * 4 + r] = Lacc[m][r];
    }
    __syncthreads();
    if (!ksel) {
        const float* mg = &sh.Mg[qsel][lane][0];
        #pragma unroll
        for (int m = 0; m < 2; m++)
            #pragma unroll
            for (int j = 0; j < 4; j++)
                #pragma unroll
                for (int r = 0; r < 4; r++)
                    O[m][j][r] += mg[m * 16 + j * 4 + r];
        #pragma unroll
        for (int m = 0; m < 2; m++)
            #pragma unroll
            for (int r = 0; r < 4; r++)
                Lacc[m][r] += mg[32 + m * 4 + r];

        #pragma unroll
        for (int m = 0; m < 2; m++) {
            f32x4 rl;
            #pragma unroll
            for (int r = 0; r < 4; r++) rl[r] = 1.0f / Lacc[m][r];
            #pragma unroll
            for (int j = 0; j < 4; j++)
                #pragma unroll
                for (int r = 0; r < 4; r++) {
                    int row = qw + m * 16 + quad * 4 + r;
                    y[((long)b * SEQ + row) * D_MODEL + h * HD + j * 16 + l16] =
                        f2bf(O[m][j][r] * rl[r]);
                }
        }
    }
}

// ---------------------------------------------------------------------------
// Workspace (48 MB): Qb@0, yb@8M, Kt2@24M, Vt2@32M, WqkvT@40M, WoT@46M.
// x_bf scratched in d_out. repack_kv fused into gemm_qkv.
// ---------------------------------------------------------------------------
extern "C" void kernel_launch(void* const* d_in, const int* in_sizes, int n_in,
                              void* d_out, int out_size, void* d_ws, size_t ws_size,
                              hipStream_t stream) {
    const float* x    = (const float*)d_in[0];
    const float* Wqkv = (const float*)d_in[1];
    const float* Wo   = (const float*)d_in[2];

    char* ws = (char*)d_ws;
    short* Qb    = (short*)(ws);
    short* Kt2   = (short*)(ws + 25165824);
    short* Vt2   = (short*)(ws + 33554432);
    short* WqkvT = (short*)(ws + 41943040);
    short* WoT   = (short*)(ws + 48234496);
    short* x_bf  = (short*)d_out;            // scratch in d_out (16 MB fp32)
    short* yb    = (short*)(ws + 8388608);

    const float cexp = 0.125f * 1.4426950408889634f;  // 1/sqrt(64) * log2(e)

    prep_kernel<<<8192, 256, 0, stream>>>(x, x_bf, Wqkv, WqkvT, Wo, WoT, cexp);

    gemm_qkv<<<dim3(3 * D_MODEL / 128, NTOK / 128), 256, 0, stream>>>(
        x_bf, WqkvT, Qb, Kt2, Vt2);

    flash_attn<<<dim3(SEQ / 64, BATCH * NHEADS), 256, 0, stream>>>(Qb, Kt2, Vt2, yb);

    gemm_out<<<dim3(D_MODEL / 128, NTOK / 128), 512, 0, stream>>>(
        yb, WoT, (float*)d_out, NTOK, D_MODEL, D_MODEL);
}

// Round 10
// 188.152 us; speedup vs baseline: 1.0648x; 1.0264x over previous
//
#include <hip/hip_runtime.h>
#include <hip/hip_bf16.h>

#define D_MODEL 1024
#define NHEADS  16
#define HD      64
#define BATCH   2
#define SEQ     2048
#define NTOK    (BATCH * SEQ)   // 4096

typedef __attribute__((ext_vector_type(8))) short bf16x8;
typedef __attribute__((ext_vector_type(4))) float f32x4;

#if __has_builtin(__builtin_amdgcn_exp2f)
#define EXP2F(x) __builtin_amdgcn_exp2f(x)   // raw v_exp_f32
#else
#define EXP2F(x) exp2f(x)
#endif

static __device__ __forceinline__ short f2bf(float f) {
    union { float f; unsigned u; } x; x.f = f;
    unsigned r = (x.u + 0x7fffu + ((x.u >> 16) & 1u)) >> 16;  // RNE
    return (short)r;
}

// pack two fp32 -> bf16 pair (RNE), as one dword
static __device__ __forceinline__ unsigned pk_bf16(float a, float b) {
    __hip_bfloat162 h2 = __float22bfloat162_rn(make_float2(a, b));
    union { __hip_bfloat162 h; unsigned u; } c; c.h = h2;
    return c.u;
}

// async global->LDS, 16B per lane; LDS dest = wave-uniform base + lane*16
static __device__ __forceinline__ void gl_lds16(const short* g, short* l) {
    __builtin_amdgcn_global_load_lds((const __attribute__((address_space(1))) void*)g,
                                     (__attribute__((address_space(3))) void*)l,
                                     16, 0, 0);
}

// ---------------------------------------------------------------------------
// Fused prep: cast x -> bf16 (blocks 0..4095), transpose+cast Wqkv with
// softmax scale folded into Q-columns (blocks 4096..7167), transpose+cast Wo
// (blocks 7168..8191). One launch instead of three.
// ---------------------------------------------------------------------------
__global__ __launch_bounds__(256) void prep_kernel(const float* __restrict__ x,
                                                   short* __restrict__ x_bf,
                                                   const float* __restrict__ Wqkv,
                                                   short* __restrict__ WqkvT,
                                                   const float* __restrict__ Wo,
                                                   short* __restrict__ WoT,
                                                   float cexp) {
    int bid = blockIdx.x;
    int tid = threadIdx.x;

    if (bid < 4096) {
        int i = bid * 256 + tid;
        float4 v = ((const float4*)x)[i];
        short4 o;
        o.x = f2bf(v.x); o.y = f2bf(v.y); o.z = f2bf(v.z); o.w = f2bf(v.w);
        ((short4*)x_bf)[i] = o;
        return;
    }

    __shared__ float tile[32][33];
    const float* in; short* out; int R, C, slimit; float sc; int bx, by;
    if (bid < 4096 + 3072) {
        int idx = bid - 4096;
        in = Wqkv; out = WqkvT; R = D_MODEL; C = 3 * D_MODEL;
        slimit = D_MODEL; sc = cexp;
        bx = idx % 96; by = idx / 96;
    } else {
        int idx = bid - 7168;
        in = Wo; out = WoT; R = D_MODEL; C = D_MODEL;
        slimit = 0; sc = 1.0f;
        bx = idx % 32; by = idx / 32;
    }
    int bc = bx * 32, br = by * 32;
    int tx = tid & 31, ty = tid >> 5;   // 32 x 8
    #pragma unroll
    for (int i = 0; i < 32; i += 8)
        tile[ty + i][tx] = in[(long)(br + ty + i) * C + bc + tx];
    __syncthreads();
    #pragma unroll
    for (int i = 0; i < 32; i += 8) {
        int orow = bc + ty + i;
        float v = tile[tx][ty + i];
        if (orow < slimit) v *= sc;
        out[(long)orow * R + br + tx] = f2bf(v);
    }
}

// ---------------------------------------------------------------------------
// Output-proj GEMM: R7 version restored (128x64 tiles, 512 blocks = 2/CU,
// BK=64 two-buffer). R9's 128x128/512-thread variant cost ~5 us (1 block/CU
// left barrier drains uncovered) — reverted.
// ---------------------------------------------------------------------------
__global__ __launch_bounds__(256) void gemm_out(const short* __restrict__ A,
                                                const short* __restrict__ BT,
                                                float* __restrict__ C,
                                                int M, int N, int K) {
    __shared__ short As[2][128 * 32];
    __shared__ short Bs[2][64 * 32];

    int tid  = threadIdx.x;
    int lane = tid & 63;
    int w    = tid >> 6;
    int quad = lane >> 4;
    int l16  = lane & 15;

    int m_blk = blockIdx.y * 128, n_blk = blockIdx.x * 64;

    const short* Ag = A  + (long)(m_blk + w * 32 + (lane >> 2)) * K + (lane & 3) * 8;
    const short* Bg = BT + (long)(n_blk + w * 16 + (lane >> 2)) * K + (lane & 3) * 8;
    short* As0 = &As[0][(w * 32) * 32];
    short* As1 = &As[1][(w * 32) * 32];
    short* Bs0 = &Bs[0][(w * 16) * 32];
    short* Bs1 = &Bs[1][(w * 16) * 32];

    f32x4 acc[2][4] = {};

    for (int k0 = 0; k0 < K; k0 += 64) {
        __syncthreads();
        gl_lds16(Ag + k0,               As0);
        gl_lds16(Ag + 16 * K + k0,      As0 + 16 * 32);
        gl_lds16(Ag + k0 + 32,          As1);
        gl_lds16(Ag + 16 * K + k0 + 32, As1 + 16 * 32);
        gl_lds16(Bg + k0,               Bs0);
        gl_lds16(Bg + k0 + 32,          Bs1);
        __syncthreads();

        #pragma unroll
        for (int kk = 0; kk < 2; kk++) {
            bf16x8 a[2], b[4];
            #pragma unroll
            for (int i = 0; i < 2; i++)
                a[i] = *(const bf16x8*)&As[kk][(w * 32 + i * 16 + l16) * 32 + quad * 8];
            #pragma unroll
            for (int j = 0; j < 4; j++)
                b[j] = *(const bf16x8*)&Bs[kk][(j * 16 + l16) * 32 + quad * 8];
            #pragma unroll
            for (int i = 0; i < 2; i++)
                #pragma unroll
                for (int j = 0; j < 4; j++)
                    acc[i][j] = __builtin_amdgcn_mfma_f32_16x16x32_bf16(a[i], b[j], acc[i][j], 0, 0, 0);
        }
    }

    #pragma unroll
    for (int i = 0; i < 2; i++)
        #pragma unroll
        for (int j = 0; j < 4; j++)
            #pragma unroll
            for (int r = 0; r < 4; r++) {
                int row = m_blk + w * 32 + i * 16 + quad * 4 + r;
                int col = n_blk + j * 16 + l16;
                C[(long)row * N + col] = acc[i][j][r];
            }
}

// ---------------------------------------------------------------------------
// QKV GEMM with FUSED repack epilogue (R6-verified) + BK=64 + XCD n-chunk
// swizzle (R7: measured neutral, kept). Epilogue bit-identical to R6.
// ---------------------------------------------------------------------------
__global__ __launch_bounds__(256) void gemm_qkv(const short* __restrict__ A,
                                                const short* __restrict__ BT,
                                                short* __restrict__ Qb,
                                                short* __restrict__ Kt2,
                                                short* __restrict__ Vt2) {
    const int K = 1024;
    __shared__ union {
        struct { short As[2][128 * 32]; short Bs[2][128 * 32]; } g;  // 32 KB
        short Tl[4][64][72];            // wave-private 64x64 epilogue tiles (36 KB)
    } sh;

    int tid  = threadIdx.x;
    int lane = tid & 63;
    int w    = tid >> 6;
    int quad = lane >> 4;
    int l16  = lane & 15;

    // dispatch-linear id; xcd = bid%8 (round-robin heuristic), bijective remap
    int bid = blockIdx.y * 24 + blockIdx.x;
    int xcd = bid & 7;
    int pos = bid >> 3;                 // 0..95
    int nb  = xcd * 3 + (pos % 3);      // n-block 0..23 (3 per XCD)
    int mb  = pos / 3;                  // m-block 0..31

    int m_blk = mb * 128, n_blk = nb * 128;
    int mh = (w >> 1) * 64, nh = (w & 1) * 64;

    int sel = nb >> 3;                  // 0:Q 1:K 2:V (uniform per block)
    int ncol0 = n_blk - sel * 1024;

    const short* Ag = A  + (long)(m_blk + w * 32 + (lane >> 2)) * K + (lane & 3) * 8;
    const short* Bg = BT + (long)(n_blk + w * 32 + (lane >> 2)) * K + (lane & 3) * 8;
    short* As0 = &sh.g.As[0][(w * 32) * 32];
    short* As1 = &sh.g.As[1][(w * 32) * 32];
    short* Bs0 = &sh.g.Bs[0][(w * 32) * 32];
    short* Bs1 = &sh.g.Bs[1][(w * 32) * 32];

    f32x4 acc[4][4] = {};

    for (int k0 = 0; k0 < K; k0 += 64) {
        __syncthreads();
        gl_lds16(Ag + k0,               As0);
        gl_lds16(Ag + 16 * K + k0,      As0 + 16 * 32);
        gl_lds16(Ag + k0 + 32,          As1);
        gl_lds16(Ag + 16 * K + k0 + 32, As1 + 16 * 32);
        gl_lds16(Bg + k0,               Bs0);
        gl_lds16(Bg + 16 * K + k0,      Bs0 + 16 * 32);
        gl_lds16(Bg + k0 + 32,          Bs1);
        gl_lds16(Bg + 16 * K + k0 + 32, Bs1 + 16 * 32);
        __syncthreads();

        #pragma unroll
        for (int kk = 0; kk < 2; kk++) {
            bf16x8 a[4], b[4];
            #pragma unroll
            for (int i = 0; i < 4; i++)
                a[i] = *(const bf16x8*)&sh.g.As[kk][(mh + i * 16 + l16) * 32 + quad * 8];
            #pragma unroll
            for (int j = 0; j < 4; j++)
                b[j] = *(const bf16x8*)&sh.g.Bs[kk][(nh + j * 16 + l16) * 32 + quad * 8];
            #pragma unroll
            for (int i = 0; i < 4; i++)
                #pragma unroll
                for (int j = 0; j < 4; j++)
                    acc[i][j] = __builtin_amdgcn_mfma_f32_16x16x32_bf16(a[i], b[j], acc[i][j], 0, 0, 0);
        }
    }

    // all waves done with As/Bs before the union is reused
    __syncthreads();

    // stage this wave's 64x64 bf16 tile into its private LDS buffer
    #pragma unroll
    for (int i = 0; i < 4; i++)
        #pragma unroll
        for (int j = 0; j < 4; j++)
            #pragma unroll
            for (int r = 0; r < 4; r++)
                sh.Tl[w][i * 16 + quad * 4 + r][j * 16 + l16] = f2bf(acc[i][j][r]);

    int R0q = m_blk + mh;                      // global token-row base of subtile
    if (sel == 0) {
        long qbase = (long)R0q * 1024 + (ncol0 + nh);
        #pragma unroll
        for (int ch = 0; ch < 8; ch++) {
            int row  = ch * 8 + (lane >> 3);
            int col0 = (lane & 7) * 8;
            *(bf16x8*)(Qb + qbase + (long)row * 1024 + col0) =
                *(const bf16x8*)&sh.Tl[w][row][col0];
        }
    } else {
        int b2 = R0q >> 11;                    // batch
        int t  = (R0q & 2047) >> 6;            // 64-key tile within sequence
        int h  = (ncol0 + nh) >> 6;            // head
        long obase = (long)(b2 * 16 + h) * (SEQ * 64) + (long)t * 4096;
        short* outT = (sel == 1) ? Kt2 : Vt2;
        if (sel == 1) {
            #pragma unroll
            for (int ch = 0; ch < 8; ch++) {
                int o = lane * 64 + ch * 8;
                int u = o >> 9, qd = (o >> 7) & 3, l = (o >> 3) & 15;
                int row = (u >> 2) * 32 + ((u >> 1) & 1) * 16 + l;
                int col = (u & 1) * 32 + qd * 8;
                *(bf16x8*)(outT + obase + o) = *(const bf16x8*)&sh.Tl[w][row][col];
            }
        } else {
            #pragma unroll
            for (int ch = 0; ch < 8; ch++) {
                int o = lane * 64 + ch * 8;
                int c = o >> 11, j2 = (o >> 9) & 3, qd = (o >> 7) & 3, l = (o >> 3) & 15;
                int hd = j2 * 16 + l;
                bf16x8 ov;
                #pragma unroll
                for (int jj = 0; jj < 8; jj++) {
                    int s = c * 32 + qd * 8 + jj;
                    int key = (s >> 2) + ((s & 3) << 4);
                    ov[jj] = sh.Tl[w][key][hd];
                }
                *(bf16x8*)(outT + obase + o) = ov;
            }
        }
    }
}

// ---------------------------------------------------------------------------
// Flash attention, round-10: LDS-STAGED K/V (attacks the real bottleneck).
//   Ledger R0-R8 reread as per-CU VMEM volume: R0 16wv x 16it x 16KB = 4MB
//   -> 56us; R4 8 x 32 x 16KB = 4MB -> 62us; R8 16 x 32 x 16KB = 8MB ->
//   81us (+44% for 2x). Duration tracks bytes-through-L1/TA (~64B/cyc),
//   explaining invariance to FETCH/occupancy/swizzle. Fix: stage each K/V
//   tile into LDS ONCE per block (global_load_lds), all 4 waves fragment-
//   read from the 128B/cyc LDS pipe. Per-CU VMEM drops 4MB -> 1MB.
//   Geometry: 128 q-rows/block (4 waves x 32 rows = R0's exact proven m=2
//   compute body), shared full 32-tile K-sweep, NO ksplit -> merge deleted.
//   Double-buffered staging, one barrier/iter: stage(t+1) issued BEFORE
//   compute(t), barrier's vmcnt drain lands after ~1800cy of compute.
//   Grid 512, R4-verified bijective XCD chunk (4 bh = 2MB per XCD L2).
//   LDS 50KB; 2 blocks/CU (grid-limited) = 8 waves/CU.
// ---------------------------------------------------------------------------
__global__ __launch_bounds__(256, 4) void flash_attn(const short* __restrict__ Qb,
                                                     const short* __restrict__ Kt2,
                                                     const short* __restrict__ Vt2,
                                                     short* __restrict__ y) {
    int tid  = threadIdx.x;
    int lane = tid & 63;
    int w    = tid >> 6;
    int quad = lane >> 4;
    int l16  = lane & 15;

    // bijective XCD-chunked swizzle (512 % 8 == 0): 64 blocks = 4 bh per XCD
    int bid0 = blockIdx.x;
    int nid  = (bid0 & 7) * 64 + (bid0 >> 3);
    int bh   = nid >> 4;
    int b    = bh >> 4;
    int h    = bh & 15;
    int qw   = (nid & 15) * 128 + w * 32;   // wave-private 32 q-rows

    __shared__ short Ks[2][4096];   // 16 KB
    __shared__ short Vs[2][4096];   // 16 KB
    __shared__ short Ps[4][32 * 72];// 18 KB wave-private P tiles
    short* PsW = &Ps[w][0];

    const short* Qrow = Qb + ((long)b * SEQ + qw + l16) * 1024 + h * 64;
    bf16x8 aQ[2][2];
    #pragma unroll
    for (int m = 0; m < 2; m++)
        #pragma unroll
        for (int c = 0; c < 2; c++)
            aQ[m][c] = *(const bf16x8*)(Qrow + (long)(m * 16) * 1024 + c * 32 + quad * 8);

    const short* Ktb = Kt2 + (long)bh * (SEQ * 64);
    const short* Vtb = Vt2 + (long)bh * (SEQ * 64);

    f32x4 O[2][4] = {};
    f32x4 Lacc[2] = {};
    bf16x8 ones;
    #pragma unroll
    for (int i = 0; i < 8; i++) ones[i] = (short)0x3F80;   // bf16 1.0

    // wave w stages shorts [w*1024, w*1024+1024) of each 4096-short tile
    // (2 x 1KB gl_lds16 calls per tile; dest base wave-uniform, src per-lane)
    int soff = w * 1024 + lane * 8;

    // prologue: stage tile 0 into buffer 0
    {
        const short* ks = Ktb + soff;
        const short* vs = Vtb + soff;
        gl_lds16(ks,       &Ks[0][w * 1024]);
        gl_lds16(ks + 512, &Ks[0][w * 1024 + 512]);
        gl_lds16(vs,       &Vs[0][w * 1024]);
        gl_lds16(vs + 512, &Vs[0][w * 1024 + 512]);
    }
    __syncthreads();

    for (int t = 0; t < 32; t++) {
        int cur = t & 1;

        // issue staging for t+1 into the other buffer (in flight during compute)
        if (t < 31) {
            const short* ks = Ktb + (t + 1) * 4096 + soff;
            const short* vs = Vtb + (t + 1) * 4096 + soff;
            gl_lds16(ks,       &Ks[cur ^ 1][w * 1024]);
            gl_lds16(ks + 512, &Ks[cur ^ 1][w * 1024 + 512]);
            gl_lds16(vs,       &Vs[cur ^ 1][w * 1024]);
            gl_lds16(vs + 512, &Vs[cur ^ 1][w * 1024 + 512]);
        }

        // K fragments from LDS (contiguous b128, conflict-free)
        bf16x8 kf[8];
        #pragma unroll
        for (int u = 0; u < 8; u++) kf[u] = *(const bf16x8*)&Ks[cur][u * 512 + lane * 8];

        // S = Q K^T: 2 m-frags x 4 key-cols, 2 chained d-chunks each
        f32x4 z[2][4];
        #pragma unroll
        for (int m = 0; m < 2; m++)
            #pragma unroll
            for (int kc = 0; kc < 4; kc++) {
                f32x4 zz = {};
                zz = __builtin_amdgcn_mfma_f32_16x16x32_bf16(aQ[m][0], kf[2 * kc],     zz, 0, 0, 0);
                z[m][kc] = __builtin_amdgcn_mfma_f32_16x16x32_bf16(aQ[m][1], kf[2 * kc + 1], zz, 0, 0, 0);
            }

        // V fragments from LDS
        bf16x8 vf[8];
        #pragma unroll
        for (int u = 0; u < 8; u++) vf[u] = *(const bf16x8*)&Vs[cur][u * 512 + lane * 8];

        // p = exp2(z); packed bf16 cvt; one b64 write per (m,r)
        #pragma unroll
        for (int m = 0; m < 2; m++)
            #pragma unroll
            for (int r = 0; r < 4; r++) {
                unsigned d0 = pk_bf16(EXP2F(z[m][0][r]), EXP2F(z[m][1][r]));
                unsigned d1 = pk_bf16(EXP2F(z[m][2][r]), EXP2F(z[m][3][r]));
                unsigned long long dd = ((unsigned long long)d1 << 32) | d0;
                *(unsigned long long*)((unsigned*)PsW + (m * 16 + quad * 4 + r) * 36 + 2 * l16) = dd;
            }

        // PV + row-sum (ones-column MFMA); bV shared across both m-frags
        #pragma unroll
        for (int c = 0; c < 2; c++) {
            bf16x8 aP0 = *(const bf16x8*)(PsW + (l16) * 72      + c * 32 + quad * 8);
            bf16x8 aP1 = *(const bf16x8*)(PsW + (16 + l16) * 72 + c * 32 + quad * 8);
            Lacc[0] = __builtin_amdgcn_mfma_f32_16x16x32_bf16(aP0, ones, Lacc[0], 0, 0, 0);
            Lacc[1] = __builtin_amdgcn_mfma_f32_16x16x32_bf16(aP1, ones, Lacc[1], 0, 0, 0);
            #pragma unroll
            for (int j = 0; j < 4; j++) {
                O[0][j] = __builtin_amdgcn_mfma_f32_16x16x32_bf16(aP0, vf[c * 4 + j], O[0][j], 0, 0, 0);
                O[1][j] = __builtin_amdgcn_mfma_f32_16x16x32_bf16(aP1, vf[c * 4 + j], O[1][j], 0, 0, 0);
            }
        }

        // drain t+1 staging (already covered by compute) + guard buffer reuse
        __syncthreads();
    }

    // direct epilogue: each wave owns its 32 rows — no merge
    #pragma unroll
    for (int m = 0; m < 2; m++) {
        f32x4 rl;
        #pragma unroll
        for (int r = 0; r < 4; r++) rl[r] = 1.0f / Lacc[m][r];
        #pragma unroll
        for (int j = 0; j < 4; j++)
            #pragma unroll
            for (int r = 0; r < 4; r++) {
                int row = qw + m * 16 + quad * 4 + r;
                y[((long)b * SEQ + row) * D_MODEL + h * HD + j * 16 + l16] =
                    f2bf(O[m][j][r] * rl[r]);
            }
    }
}

// ---------------------------------------------------------------------------
// Workspace (48 MB): Qb@0, yb@8M, Kt2@24M, Vt2@32M, WqkvT@40M, WoT@46M.
// x_bf scratched in d_out. repack_kv fused into gemm_qkv.
// ---------------------------------------------------------------------------
extern "C" void kernel_launch(void* const* d_in, const int* in_sizes, int n_in,
                              void* d_out, int out_size, void* d_ws, size_t ws_size,
                              hipStream_t stream) {
    const float* x    = (const float*)d_in[0];
    const float* Wqkv = (const float*)d_in[1];
    const float* Wo   = (const float*)d_in[2];

    char* ws = (char*)d_ws;
    short* Qb    = (short*)(ws);
    short* Kt2   = (short*)(ws + 25165824);
    short* Vt2   = (short*)(ws + 33554432);
    short* WqkvT = (short*)(ws + 41943040);
    short* WoT   = (short*)(ws + 48234496);
    short* x_bf  = (short*)d_out;            // scratch in d_out (16 MB fp32)
    short* yb    = (short*)(ws + 8388608);

    const float cexp = 0.125f * 1.4426950408889634f;  // 1/sqrt(64) * log2(e)

    prep_kernel<<<8192, 256, 0, stream>>>(x, x_bf, Wqkv, WqkvT, Wo, WoT, cexp);

    gemm_qkv<<<dim3(3 * D_MODEL / 128, NTOK / 128), 256, 0, stream>>>(
        x_bf, WqkvT, Qb, Kt2, Vt2);

    flash_attn<<<512, 256, 0, stream>>>(Qb, Kt2, Vt2, yb);

    gemm_out<<<dim3(D_MODEL / 64, NTOK / 128), 256, 0, stream>>>(
        yb, WoT, (float*)d_out, NTOK, D_MODEL, D_MODEL);
}

// Round 12
// 187.897 us; speedup vs baseline: 1.0663x; 1.0014x over previous
//
#include <hip/hip_runtime.h>
#include <hip/hip_bf16.h>

#define D_MODEL 1024
#define NHEADS  16
#define HD      64
#define BATCH   2
#define SEQ     2048
#define NTOK    (BATCH * SEQ)   // 4096

typedef __attribute__((ext_vector_type(8))) short bf16x8;
typedef __attribute__((ext_vector_type(4))) float f32x4;

#if __has_builtin(__builtin_amdgcn_exp2f)
#define EXP2F(x) __builtin_amdgcn_exp2f(x)   // raw v_exp_f32
#else
#define EXP2F(x) exp2f(x)
#endif

static __device__ __forceinline__ short f2bf(float f) {
    union { float f; unsigned u; } x; x.f = f;
    unsigned r = (x.u + 0x7fffu + ((x.u >> 16) & 1u)) >> 16;  // RNE
    return (short)r;
}

// pack two fp32 -> bf16 pair (RNE), as one dword
static __device__ __forceinline__ unsigned pk_bf16(float a, float b) {
    __hip_bfloat162 h2 = __float22bfloat162_rn(make_float2(a, b));
    union { __hip_bfloat162 h; unsigned u; } c; c.h = h2;
    return c.u;
}

// async global->LDS, 16B per lane; LDS dest = wave-uniform base + lane*16
static __device__ __forceinline__ void gl_lds16(const short* g, short* l) {
    __builtin_amdgcn_global_load_lds((const __attribute__((address_space(1))) void*)g,
                                     (__attribute__((address_space(3))) void*)l,
                                     16, 0, 0);
}

// ---------------------------------------------------------------------------
// Fused prep: cast x -> bf16 (blocks 0..4095), transpose+cast Wqkv with
// softmax scale folded into Q-columns (blocks 4096..7167), transpose+cast Wo
// (blocks 7168..8191). One launch instead of three.
// ---------------------------------------------------------------------------
__global__ __launch_bounds__(256) void prep_kernel(const float* __restrict__ x,
                                                   short* __restrict__ x_bf,
                                                   const float* __restrict__ Wqkv,
                                                   short* __restrict__ WqkvT,
                                                   const float* __restrict__ Wo,
                                                   short* __restrict__ WoT,
                                                   float cexp) {
    int bid = blockIdx.x;
    int tid = threadIdx.x;

    if (bid < 4096) {
        int i = bid * 256 + tid;
        float4 v = ((const float4*)x)[i];
        short4 o;
        o.x = f2bf(v.x); o.y = f2bf(v.y); o.z = f2bf(v.z); o.w = f2bf(v.w);
        ((short4*)x_bf)[i] = o;
        return;
    }

    __shared__ float tile[32][33];
    const float* in; short* out; int R, C, slimit; float sc; int bx, by;
    if (bid < 4096 + 3072) {
        int idx = bid - 4096;
        in = Wqkv; out = WqkvT; R = D_MODEL; C = 3 * D_MODEL;
        slimit = D_MODEL; sc = cexp;
        bx = idx % 96; by = idx / 96;
    } else {
        int idx = bid - 7168;
        in = Wo; out = WoT; R = D_MODEL; C = D_MODEL;
        slimit = 0; sc = 1.0f;
        bx = idx % 32; by = idx / 32;
    }
    int bc = bx * 32, br = by * 32;
    int tx = tid & 31, ty = tid >> 5;   // 32 x 8
    #pragma unroll
    for (int i = 0; i < 32; i += 8)
        tile[ty + i][tx] = in[(long)(br + ty + i) * C + bc + tx];
    __syncthreads();
    #pragma unroll
    for (int i = 0; i < 32; i += 8) {
        int orow = bc + ty + i;
        float v = tile[tx][ty + i];
        if (orow < slimit) v *= sc;
        out[(long)orow * R + br + tx] = f2bf(v);
    }
}

// ---------------------------------------------------------------------------
// Output-proj GEMM: 128x64 tiles, 512 blocks = 2/CU, BK=64 two-buffer
// (R7 config, part of the 188 us best).
// ---------------------------------------------------------------------------
__global__ __launch_bounds__(256) void gemm_out(const short* __restrict__ A,
                                                const short* __restrict__ BT,
                                                float* __restrict__ C,
                                                int M, int N, int K) {
    __shared__ short As[2][128 * 32];
    __shared__ short Bs[2][64 * 32];

    int tid  = threadIdx.x;
    int lane = tid & 63;
    int w    = tid >> 6;
    int quad = lane >> 4;
    int l16  = lane & 15;

    int m_blk = blockIdx.y * 128, n_blk = blockIdx.x * 64;

    const short* Ag = A  + (long)(m_blk + w * 32 + (lane >> 2)) * K + (lane & 3) * 8;
    const short* Bg = BT + (long)(n_blk + w * 16 + (lane >> 2)) * K + (lane & 3) * 8;
    short* As0 = &As[0][(w * 32) * 32];
    short* As1 = &As[1][(w * 32) * 32];
    short* Bs0 = &Bs[0][(w * 16) * 32];
    short* Bs1 = &Bs[1][(w * 16) * 32];

    f32x4 acc[2][4] = {};

    for (int k0 = 0; k0 < K; k0 += 64) {
        __syncthreads();
        gl_lds16(Ag + k0,               As0);
        gl_lds16(Ag + 16 * K + k0,      As0 + 16 * 32);
        gl_lds16(Ag + k0 + 32,          As1);
        gl_lds16(Ag + 16 * K + k0 + 32, As1 + 16 * 32);
        gl_lds16(Bg + k0,               Bs0);
        gl_lds16(Bg + k0 + 32,          Bs1);
        __syncthreads();

        #pragma unroll
        for (int kk = 0; kk < 2; kk++) {
            bf16x8 a[2], b[4];
            #pragma unroll
            for (int i = 0; i < 2; i++)
                a[i] = *(const bf16x8*)&As[kk][(w * 32 + i * 16 + l16) * 32 + quad * 8];
            #pragma unroll
            for (int j = 0; j < 4; j++)
                b[j] = *(const bf16x8*)&Bs[kk][(j * 16 + l16) * 32 + quad * 8];
            #pragma unroll
            for (int i = 0; i < 2; i++)
                #pragma unroll
                for (int j = 0; j < 4; j++)
                    acc[i][j] = __builtin_amdgcn_mfma_f32_16x16x32_bf16(a[i], b[j], acc[i][j], 0, 0, 0);
        }
    }

    #pragma unroll
    for (int i = 0; i < 2; i++)
        #pragma unroll
        for (int j = 0; j < 4; j++)
            #pragma unroll
            for (int r = 0; r < 4; r++) {
                int row = m_blk + w * 32 + i * 16 + quad * 4 + r;
                int col = n_blk + j * 16 + l16;
                C[(long)row * N + col] = acc[i][j][r];
            }
}

// ---------------------------------------------------------------------------
// QKV GEMM with FUSED repack epilogue (R6-verified) + BK=64 + XCD n-chunk
// swizzle (R7: neutral, kept). Epilogue bit-identical to R6.
// ---------------------------------------------------------------------------
__global__ __launch_bounds__(256) void gemm_qkv(const short* __restrict__ A,
                                                const short* __restrict__ BT,
                                                short* __restrict__ Qb,
                                                short* __restrict__ Kt2,
                                                short* __restrict__ Vt2) {
    const int K = 1024;
    __shared__ union {
        struct { short As[2][128 * 32]; short Bs[2][128 * 32]; } g;  // 32 KB
        short Tl[4][64][72];            // wave-private 64x64 epilogue tiles (36 KB)
    } sh;

    int tid  = threadIdx.x;
    int lane = tid & 63;
    int w    = tid >> 6;
    int quad = lane >> 4;
    int l16  = lane & 15;

    // dispatch-linear id; xcd = bid%8 (round-robin heuristic), bijective remap
    int bid = blockIdx.y * 24 + blockIdx.x;
    int xcd = bid & 7;
    int pos = bid >> 3;                 // 0..95
    int nb  = xcd * 3 + (pos % 3);      // n-block 0..23 (3 per XCD)
    int mb  = pos / 3;                  // m-block 0..31

    int m_blk = mb * 128, n_blk = nb * 128;
    int mh = (w >> 1) * 64, nh = (w & 1) * 64;

    int sel = nb >> 3;                  // 0:Q 1:K 2:V (uniform per block)
    int ncol0 = n_blk - sel * 1024;

    const short* Ag = A  + (long)(m_blk + w * 32 + (lane >> 2)) * K + (lane & 3) * 8;
    const short* Bg = BT + (long)(n_blk + w * 32 + (lane >> 2)) * K + (lane & 3) * 8;
    short* As0 = &sh.g.As[0][(w * 32) * 32];
    short* As1 = &sh.g.As[1][(w * 32) * 32];
    short* Bs0 = &sh.g.Bs[0][(w * 32) * 32];
    short* Bs1 = &sh.g.Bs[1][(w * 32) * 32];

    f32x4 acc[4][4] = {};

    for (int k0 = 0; k0 < K; k0 += 64) {
        __syncthreads();
        gl_lds16(Ag + k0,               As0);
        gl_lds16(Ag + 16 * K + k0,      As0 + 16 * 32);
        gl_lds16(Ag + k0 + 32,          As1);
        gl_lds16(Ag + 16 * K + k0 + 32, As1 + 16 * 32);
        gl_lds16(Bg + k0,               Bs0);
        gl_lds16(Bg + 16 * K + k0,      Bs0 + 16 * 32);
        gl_lds16(Bg + k0 + 32,          Bs1);
        gl_lds16(Bg + 16 * K + k0 + 32, Bs1 + 16 * 32);
        __syncthreads();

        #pragma unroll
        for (int kk = 0; kk < 2; kk++) {
            bf16x8 a[4], b[4];
            #pragma unroll
            for (int i = 0; i < 4; i++)
                a[i] = *(const bf16x8*)&sh.g.As[kk][(mh + i * 16 + l16) * 32 + quad * 8];
            #pragma unroll
            for (int j = 0; j < 4; j++)
                b[j] = *(const bf16x8*)&sh.g.Bs[kk][(nh + j * 16 + l16) * 32 + quad * 8];
            #pragma unroll
            for (int i = 0; i < 4; i++)
                #pragma unroll
                for (int j = 0; j < 4; j++)
                    acc[i][j] = __builtin_amdgcn_mfma_f32_16x16x32_bf16(a[i], b[j], acc[i][j], 0, 0, 0);
        }
    }

    // all waves done with As/Bs before the union is reused
    __syncthreads();

    // stage this wave's 64x64 bf16 tile into its private LDS buffer
    #pragma unroll
    for (int i = 0; i < 4; i++)
        #pragma unroll
        for (int j = 0; j < 4; j++)
            #pragma unroll
            for (int r = 0; r < 4; r++)
                sh.Tl[w][i * 16 + quad * 4 + r][j * 16 + l16] = f2bf(acc[i][j][r]);

    int R0q = m_blk + mh;                      // global token-row base of subtile
    if (sel == 0) {
        long qbase = (long)R0q * 1024 + (ncol0 + nh);
        #pragma unroll
        for (int ch = 0; ch < 8; ch++) {
            int row  = ch * 8 + (lane >> 3);
            int col0 = (lane & 7) * 8;
            *(bf16x8*)(Qb + qbase + (long)row * 1024 + col0) =
                *(const bf16x8*)&sh.Tl[w][row][col0];
        }
    } else {
        int b2 = R0q >> 11;                    // batch
        int t  = (R0q & 2047) >> 6;            // 64-key tile within sequence
        int h  = (ncol0 + nh) >> 6;            // head
        long obase = (long)(b2 * 16 + h) * (SEQ * 64) + (long)t * 4096;
        short* outT = (sel == 1) ? Kt2 : Vt2;
        if (sel == 1) {
            #pragma unroll
            for (int ch = 0; ch < 8; ch++) {
                int o = lane * 64 + ch * 8;
                int u = o >> 9, qd = (o >> 7) & 3, l = (o >> 3) & 15;
                int row = (u >> 2) * 32 + ((u >> 1) & 1) * 16 + l;
                int col = (u & 1) * 32 + qd * 8;
                *(bf16x8*)(outT + obase + o) = *(const bf16x8*)&sh.Tl[w][row][col];
            }
        } else {
            #pragma unroll
            for (int ch = 0; ch < 8; ch++) {
                int o = lane * 64 + ch * 8;
                int c = o >> 11, j2 = (o >> 9) & 3, qd = (o >> 7) & 3, l = (o >> 3) & 15;
                int hd = j2 * 16 + l;
                bf16x8 ov;
                #pragma unroll
                for (int jj = 0; jj < 8; jj++) {
                    int s = c * 32 + qd * 8 + jj;
                    int key = (s >> 2) + ((s & 3) << 4);
                    ov[jj] = sh.Tl[w][key][hd];
                }
                *(bf16x8*)(outT + obase + o) = ov;
            }
        }
    }
}

// ---------------------------------------------------------------------------
// Flash attention, round-12: IN-REGISTER P, CORRECTED lane algebra.
//   R11's failure diagnosed: P slot s must hold key(s) = (s>>2)+((s&3)<<4)
//   (the V-scramble invariant), so a slot-dword holds keys (k, k+16) — a
//   CROSS-kc pair. Correct packing (verified element-wise, e.g. slot63 ->
//   key63, slot0 -> key0):
//     z2[m][kc][r] at lane (q',l') = P[q=l'][key=16kc+4q'+r]   (swapped MFMA)
//     pA[m][r] = pk(exp z2[m][0][r], exp z2[m][1][r])  keys (4q'+r, +16)
//     pB[m][r] = pk(exp z2[m][2][r], exp z2[m][3][r])  keys (+32, +48)
//   A-frag dwords for (m,c) at lane (quad,l16): src lane = c*32+(quad>>1)*16
//   +l16, r0 = 2*(quad&1): dw0=pA[r0], dw1=pB[r0], dw2=pA[r0+1], dw3=pB[r0+1].
//   8 shfl + 4 select per (m,c) replace the P LDS roundtrip (the proven
//   bottleneck: R0-R10 dur invariant to all load-side levers, R10 staging
//   regressed). O/Lacc/merge/epilogue byte-identical to R0.
//   Tripwires: absmax must stay 0.001953125; WRITE_SIZE >> 13 MB = spill.
// ---------------------------------------------------------------------------
__global__ __launch_bounds__(256, 4) void flash_attn(const short* __restrict__ Qb,
                                                     const short* __restrict__ Kt2,
                                                     const short* __restrict__ Vt2,
                                                     short* __restrict__ y) {
    int tid  = threadIdx.x;
    int lane = tid & 63;
    int w    = tid >> 6;
    int quad = lane >> 4;
    int l16  = lane & 15;
    int qsel = w & 1;
    int ksel = w >> 1;

    int bh = blockIdx.y;
    int b  = bh >> 4;
    int h  = bh & 15;
    int qw = blockIdx.x * 64 + qsel * 32;

    __shared__ float Mg[2][64][41];   // merge buffers (20992 B)

    const short* Qrow = Qb + ((long)b * SEQ + qw + l16) * 1024 + h * 64;
    bf16x8 aQ[2][2];
    #pragma unroll
    for (int m = 0; m < 2; m++)
        #pragma unroll
        for (int c = 0; c < 2; c++)
            aQ[m][c] = *(const bf16x8*)(Qrow + (long)(m * 16) * 1024 + c * 32 + quad * 8);

    const short* Ktb = Kt2 + (long)bh * (SEQ * 64) + (long)ksel * 16 * 4096;
    const short* Vtb = Vt2 + (long)bh * (SEQ * 64) + (long)ksel * 16 * 4096;

    f32x4 O[2][4] = {};
    f32x4 Lacc[2] = {};
    bf16x8 ones;
    #pragma unroll
    for (int i = 0; i < 8; i++) ones[i] = (short)0x3F80;   // bf16 1.0

    int srcbase = (quad >> 1) * 16 + l16;   // + c*32 at use site
    bool oddq = (quad & 1) != 0;

    for (int t = 0; t < 16; t++) {
        const short* Kt = Ktb + t * 4096;
        const short* Vt = Vtb + t * 4096;

        // K fragment loads (coalesced 1KB dwordx4)
        bf16x8 kf[8];
        #pragma unroll
        for (int u = 0; u < 8; u++) kf[u] = *(const bf16x8*)(Kt + u * 512 + lane * 8);

        // S^T = K Q^T (operand-swapped): z2[m][kc][r] at lane (quad,l16)
        // = P[q=qw+16m+l16][key=16kc+4quad+r]
        f32x4 z2[2][4];
        #pragma unroll
        for (int m = 0; m < 2; m++)
            #pragma unroll
            for (int kc = 0; kc < 4; kc++) {
                f32x4 zz = {};
                zz = __builtin_amdgcn_mfma_f32_16x16x32_bf16(kf[2 * kc],     aQ[m][0], zz, 0, 0, 0);
                z2[m][kc] = __builtin_amdgcn_mfma_f32_16x16x32_bf16(kf[2 * kc + 1], aQ[m][1], zz, 0, 0, 0);
            }

        // V fragment loads — issued now, consumed after exp/shuffle
        bf16x8 vf[8];
        #pragma unroll
        for (int u = 0; u < 8; u++) vf[u] = *(const bf16x8*)(Vt + u * 512 + lane * 8);

        // exp + CROSS-kc pack: pA keys (4quad+r, +16); pB keys (+32, +48)
        unsigned pA[2][4], pB[2][4];
        #pragma unroll
        for (int m = 0; m < 2; m++)
            #pragma unroll
            for (int r = 0; r < 4; r++) {
                pA[m][r] = pk_bf16(EXP2F(z2[m][0][r]), EXP2F(z2[m][1][r]));
                pB[m][r] = pk_bf16(EXP2F(z2[m][2][r]), EXP2F(z2[m][3][r]));
            }

        // shuffle-assemble A-frags and run row-sum + PV per (m,c)
        #pragma unroll
        for (int m = 0; m < 2; m++)
            #pragma unroll
            for (int c = 0; c < 2; c++) {
                int src = c * 32 + srcbase;
                unsigned a0 = (unsigned)__shfl((int)pA[m][0], src);
                unsigned a1 = (unsigned)__shfl((int)pA[m][1], src);
                unsigned a2 = (unsigned)__shfl((int)pA[m][2], src);
                unsigned a3 = (unsigned)__shfl((int)pA[m][3], src);
                unsigned b0 = (unsigned)__shfl((int)pB[m][0], src);
                unsigned b1 = (unsigned)__shfl((int)pB[m][1], src);
                unsigned b2 = (unsigned)__shfl((int)pB[m][2], src);
                unsigned b3 = (unsigned)__shfl((int)pB[m][3], src);
                union { unsigned u[4]; bf16x8 v; } cvt;
                cvt.u[0] = oddq ? a2 : a0;
                cvt.u[1] = oddq ? b2 : b0;
                cvt.u[2] = oddq ? a3 : a1;
                cvt.u[3] = oddq ? b3 : b1;
                bf16x8 aP = cvt.v;

                Lacc[m] = __builtin_amdgcn_mfma_f32_16x16x32_bf16(aP, ones, Lacc[m], 0, 0, 0);
                #pragma unroll
                for (int j = 0; j < 4; j++)
                    O[m][j] = __builtin_amdgcn_mfma_f32_16x16x32_bf16(aP, vf[c * 4 + j], O[m][j], 0, 0, 0);
            }
    }

    // additive merge of key-split partners (w, w+2)
    __syncthreads();
    if (ksel) {
        float* mg = &Mg[qsel][lane][0];
        #pragma unroll
        for (int m = 0; m < 2; m++)
            #pragma unroll
            for (int j = 0; j < 4; j++)
                #pragma unroll
                for (int r = 0; r < 4; r++)
                    mg[m * 16 + j * 4 + r] = O[m][j][r];
        #pragma unroll
        for (int m = 0; m < 2; m++)
            #pragma unroll
            for (int r = 0; r < 4; r++)
                mg[32 + m * 4 + r] = Lacc[m][r];
    }
    __syncthreads();
    if (!ksel) {
        const float* mg = &Mg[qsel][lane][0];
        #pragma unroll
        for (int m = 0; m < 2; m++)
            #pragma unroll
            for (int j = 0; j < 4; j++)
                #pragma unroll
                for (int r = 0; r < 4; r++)
                    O[m][j][r] += mg[m * 16 + j * 4 + r];
        #pragma unroll
        for (int m = 0; m < 2; m++)
            #pragma unroll
            for (int r = 0; r < 4; r++)
                Lacc[m][r] += mg[32 + m * 4 + r];

        #pragma unroll
        for (int m = 0; m < 2; m++) {
            f32x4 rl;
            #pragma unroll
            for (int r = 0; r < 4; r++) rl[r] = 1.0f / Lacc[m][r];
            #pragma unroll
            for (int j = 0; j < 4; j++)
                #pragma unroll
                for (int r = 0; r < 4; r++) {
                    int row = qw + m * 16 + quad * 4 + r;
                    y[((long)b * SEQ + row) * D_MODEL + h * HD + j * 16 + l16] =
                        f2bf(O[m][j][r] * rl[r]);
                }
        }
    }
}

// ---------------------------------------------------------------------------
// Workspace (48 MB): Qb@0, yb@8M, Kt2@24M, Vt2@32M, WqkvT@40M, WoT@46M.
// x_bf scratched in d_out. repack_kv fused into gemm_qkv.
// ---------------------------------------------------------------------------
extern "C" void kernel_launch(void* const* d_in, const int* in_sizes, int n_in,
                              void* d_out, int out_size, void* d_ws, size_t ws_size,
                              hipStream_t stream) {
    const float* x    = (const float*)d_in[0];
    const float* Wqkv = (const float*)d_in[1];
    const float* Wo   = (const float*)d_in[2];

    char* ws = (char*)d_ws;
    short* Qb    = (short*)(ws);
    short* Kt2   = (short*)(ws + 25165824);
    short* Vt2   = (short*)(ws + 33554432);
    short* WqkvT = (short*)(ws + 41943040);
    short* WoT   = (short*)(ws + 48234496);
    short* x_bf  = (short*)d_out;            // scratch in d_out (16 MB fp32)
    short* yb    = (short*)(ws + 8388608);

    const float cexp = 0.125f * 1.4426950408889634f;  // 1/sqrt(64) * log2(e)

    prep_kernel<<<8192, 256, 0, stream>>>(x, x_bf, Wqkv, WqkvT, Wo, WoT, cexp);

    gemm_qkv<<<dim3(3 * D_MODEL / 128, NTOK / 128), 256, 0, stream>>>(
        x_bf, WqkvT, Qb, Kt2, Vt2);

    flash_attn<<<dim3(SEQ / 64, BATCH * NHEADS), 256, 0, stream>>>(Qb, Kt2, Vt2, yb);

    gemm_out<<<dim3(D_MODEL / 64, NTOK / 128), 256, 0, stream>>>(
        yb, WoT, (float*)d_out, NTOK, D_MODEL, D_MODEL);
}

// Round 13
// 180.479 us; speedup vs baseline: 1.1101x; 1.0411x over previous
//
#include <hip/hip_runtime.h>
#include <hip/hip_bf16.h>

#define D_MODEL 1024
#define NHEADS  16
#define HD      64
#define BATCH   2
#define SEQ     2048
#define NTOK    (BATCH * SEQ)   // 4096

typedef __attribute__((ext_vector_type(8))) short bf16x8;
typedef __attribute__((ext_vector_type(4))) float f32x4;

#if __has_builtin(__builtin_amdgcn_exp2f)
#define EXP2F(x) __builtin_amdgcn_exp2f(x)   // raw v_exp_f32
#else
#define EXP2F(x) exp2f(x)
#endif

static __device__ __forceinline__ short f2bf(float f) {
    union { float f; unsigned u; } x; x.f = f;
    unsigned r = (x.u + 0x7fffu + ((x.u >> 16) & 1u)) >> 16;  // RNE
    return (short)r;
}

// pack two fp32 -> bf16 pair (RNE), as one dword
static __device__ __forceinline__ unsigned pk_bf16(float a, float b) {
    __hip_bfloat162 h2 = __float22bfloat162_rn(make_float2(a, b));
    union { __hip_bfloat162 h; unsigned u; } c; c.h = h2;
    return c.u;
}

// async global->LDS, 16B per lane; LDS dest = wave-uniform base + lane*16
static __device__ __forceinline__ void gl_lds16(const short* g, short* l) {
    __builtin_amdgcn_global_load_lds((const __attribute__((address_space(1))) void*)g,
                                     (__attribute__((address_space(3))) void*)l,
                                     16, 0, 0);
}

// ---------------------------------------------------------------------------
// Fused prep: cast x -> bf16 (blocks 0..4095), transpose+cast Wqkv with
// softmax scale folded into Q-columns (blocks 4096..7167), transpose+cast Wo
// (blocks 7168..8191). One launch instead of three.
// ---------------------------------------------------------------------------
__global__ __launch_bounds__(256) void prep_kernel(const float* __restrict__ x,
                                                   short* __restrict__ x_bf,
                                                   const float* __restrict__ Wqkv,
                                                   short* __restrict__ WqkvT,
                                                   const float* __restrict__ Wo,
                                                   short* __restrict__ WoT,
                                                   float cexp) {
    int bid = blockIdx.x;
    int tid = threadIdx.x;

    if (bid < 4096) {
        int i = bid * 256 + tid;
        float4 v = ((const float4*)x)[i];
        short4 o;
        o.x = f2bf(v.x); o.y = f2bf(v.y); o.z = f2bf(v.z); o.w = f2bf(v.w);
        ((short4*)x_bf)[i] = o;
        return;
    }

    __shared__ float tile[32][33];
    const float* in; short* out; int R, C, slimit; float sc; int bx, by;
    if (bid < 4096 + 3072) {
        int idx = bid - 4096;
        in = Wqkv; out = WqkvT; R = D_MODEL; C = 3 * D_MODEL;
        slimit = D_MODEL; sc = cexp;
        bx = idx % 96; by = idx / 96;
    } else {
        int idx = bid - 7168;
        in = Wo; out = WoT; R = D_MODEL; C = D_MODEL;
        slimit = 0; sc = 1.0f;
        bx = idx % 32; by = idx / 32;
    }
    int bc = bx * 32, br = by * 32;
    int tx = tid & 31, ty = tid >> 5;   // 32 x 8
    #pragma unroll
    for (int i = 0; i < 32; i += 8)
        tile[ty + i][tx] = in[(long)(br + ty + i) * C + bc + tx];
    __syncthreads();
    #pragma unroll
    for (int i = 0; i < 32; i += 8) {
        int orow = bc + ty + i;
        float v = tile[tx][ty + i];
        if (orow < slimit) v *= sc;
        out[(long)orow * R + br + tx] = f2bf(v);
    }
}

// ---------------------------------------------------------------------------
// Output-proj GEMM: 128x64 tiles, 512 blocks = 2/CU, BK=64 two-buffer
// (R7 config, part of the 188 us best).
// ---------------------------------------------------------------------------
__global__ __launch_bounds__(256) void gemm_out(const short* __restrict__ A,
                                                const short* __restrict__ BT,
                                                float* __restrict__ C,
                                                int M, int N, int K) {
    __shared__ short As[2][128 * 32];
    __shared__ short Bs[2][64 * 32];

    int tid  = threadIdx.x;
    int lane = tid & 63;
    int w    = tid >> 6;
    int quad = lane >> 4;
    int l16  = lane & 15;

    int m_blk = blockIdx.y * 128, n_blk = blockIdx.x * 64;

    const short* Ag = A  + (long)(m_blk + w * 32 + (lane >> 2)) * K + (lane & 3) * 8;
    const short* Bg = BT + (long)(n_blk + w * 16 + (lane >> 2)) * K + (lane & 3) * 8;
    short* As0 = &As[0][(w * 32) * 32];
    short* As1 = &As[1][(w * 32) * 32];
    short* Bs0 = &Bs[0][(w * 16) * 32];
    short* Bs1 = &Bs[1][(w * 16) * 32];

    f32x4 acc[2][4] = {};

    for (int k0 = 0; k0 < K; k0 += 64) {
        __syncthreads();
        gl_lds16(Ag + k0,               As0);
        gl_lds16(Ag + 16 * K + k0,      As0 + 16 * 32);
        gl_lds16(Ag + k0 + 32,          As1);
        gl_lds16(Ag + 16 * K + k0 + 32, As1 + 16 * 32);
        gl_lds16(Bg + k0,               Bs0);
        gl_lds16(Bg + k0 + 32,          Bs1);
        __syncthreads();

        #pragma unroll
        for (int kk = 0; kk < 2; kk++) {
            bf16x8 a[2], b[4];
            #pragma unroll
            for (int i = 0; i < 2; i++)
                a[i] = *(const bf16x8*)&As[kk][(w * 32 + i * 16 + l16) * 32 + quad * 8];
            #pragma unroll
            for (int j = 0; j < 4; j++)
                b[j] = *(const bf16x8*)&Bs[kk][(j * 16 + l16) * 32 + quad * 8];
            #pragma unroll
            for (int i = 0; i < 2; i++)
                #pragma unroll
                for (int j = 0; j < 4; j++)
                    acc[i][j] = __builtin_amdgcn_mfma_f32_16x16x32_bf16(a[i], b[j], acc[i][j], 0, 0, 0);
        }
    }

    #pragma unroll
    for (int i = 0; i < 2; i++)
        #pragma unroll
        for (int j = 0; j < 4; j++)
            #pragma unroll
            for (int r = 0; r < 4; r++) {
                int row = m_blk + w * 32 + i * 16 + quad * 4 + r;
                int col = n_blk + j * 16 + l16;
                C[(long)row * N + col] = acc[i][j][r];
            }
}

// ---------------------------------------------------------------------------
// QKV GEMM with FUSED repack epilogue + BK=64 + XCD n-chunk swizzle.
// ROUND-13 CHANGE: V-scramble formula replaced by the zero-shuffle mapping
//   key(s) = (s&0x20) | ((s&0x04)<<2) | ((s&0x18)>>1) | (s&0x03)
// (bit permutation s{5,2,4,3,1,0} -> key{5..0}, bijective), chosen so that
// flash's PV A-fragment is exactly the lane-local z2 registers of the
// swapped QK^T — no shuffles needed (see flash comment). K path unchanged.
// ---------------------------------------------------------------------------
__global__ __launch_bounds__(256) void gemm_qkv(const short* __restrict__ A,
                                                const short* __restrict__ BT,
                                                short* __restrict__ Qb,
                                                short* __restrict__ Kt2,
                                                short* __restrict__ Vt2) {
    const int K = 1024;
    __shared__ union {
        struct { short As[2][128 * 32]; short Bs[2][128 * 32]; } g;  // 32 KB
        short Tl[4][64][72];            // wave-private 64x64 epilogue tiles (36 KB)
    } sh;

    int tid  = threadIdx.x;
    int lane = tid & 63;
    int w    = tid >> 6;
    int quad = lane >> 4;
    int l16  = lane & 15;

    // dispatch-linear id; xcd = bid%8 (round-robin heuristic), bijective remap
    int bid = blockIdx.y * 24 + blockIdx.x;
    int xcd = bid & 7;
    int pos = bid >> 3;                 // 0..95
    int nb  = xcd * 3 + (pos % 3);      // n-block 0..23 (3 per XCD)
    int mb  = pos / 3;                  // m-block 0..31

    int m_blk = mb * 128, n_blk = nb * 128;
    int mh = (w >> 1) * 64, nh = (w & 1) * 64;

    int sel = nb >> 3;                  // 0:Q 1:K 2:V (uniform per block)
    int ncol0 = n_blk - sel * 1024;

    const short* Ag = A  + (long)(m_blk + w * 32 + (lane >> 2)) * K + (lane & 3) * 8;
    const short* Bg = BT + (long)(n_blk + w * 32 + (lane >> 2)) * K + (lane & 3) * 8;
    short* As0 = &sh.g.As[0][(w * 32) * 32];
    short* As1 = &sh.g.As[1][(w * 32) * 32];
    short* Bs0 = &sh.g.Bs[0][(w * 32) * 32];
    short* Bs1 = &sh.g.Bs[1][(w * 32) * 32];

    f32x4 acc[4][4] = {};

    for (int k0 = 0; k0 < K; k0 += 64) {
        __syncthreads();
        gl_lds16(Ag + k0,               As0);
        gl_lds16(Ag + 16 * K + k0,      As0 + 16 * 32);
        gl_lds16(Ag + k0 + 32,          As1);
        gl_lds16(Ag + 16 * K + k0 + 32, As1 + 16 * 32);
        gl_lds16(Bg + k0,               Bs0);
        gl_lds16(Bg + 16 * K + k0,      Bs0 + 16 * 32);
        gl_lds16(Bg + k0 + 32,          Bs1);
        gl_lds16(Bg + 16 * K + k0 + 32, Bs1 + 16 * 32);
        __syncthreads();

        #pragma unroll
        for (int kk = 0; kk < 2; kk++) {
            bf16x8 a[4], b[4];
            #pragma unroll
            for (int i = 0; i < 4; i++)
                a[i] = *(const bf16x8*)&sh.g.As[kk][(mh + i * 16 + l16) * 32 + quad * 8];
            #pragma unroll
            for (int j = 0; j < 4; j++)
                b[j] = *(const bf16x8*)&sh.g.Bs[kk][(nh + j * 16 + l16) * 32 + quad * 8];
            #pragma unroll
            for (int i = 0; i < 4; i++)
                #pragma unroll
                for (int j = 0; j < 4; j++)
                    acc[i][j] = __builtin_amdgcn_mfma_f32_16x16x32_bf16(a[i], b[j], acc[i][j], 0, 0, 0);
        }
    }

    // all waves done with As/Bs before the union is reused
    __syncthreads();

    // stage this wave's 64x64 bf16 tile into its private LDS buffer
    #pragma unroll
    for (int i = 0; i < 4; i++)
        #pragma unroll
        for (int j = 0; j < 4; j++)
            #pragma unroll
            for (int r = 0; r < 4; r++)
                sh.Tl[w][i * 16 + quad * 4 + r][j * 16 + l16] = f2bf(acc[i][j][r]);

    int R0q = m_blk + mh;                      // global token-row base of subtile
    if (sel == 0) {
        long qbase = (long)R0q * 1024 + (ncol0 + nh);
        #pragma unroll
        for (int ch = 0; ch < 8; ch++) {
            int row  = ch * 8 + (lane >> 3);
            int col0 = (lane & 7) * 8;
            *(bf16x8*)(Qb + qbase + (long)row * 1024 + col0) =
                *(const bf16x8*)&sh.Tl[w][row][col0];
        }
    } else {
        int b2 = R0q >> 11;                    // batch
        int t  = (R0q & 2047) >> 6;            // 64-key tile within sequence
        int h  = (ncol0 + nh) >> 6;            // head
        long obase = (long)(b2 * 16 + h) * (SEQ * 64) + (long)t * 4096;
        short* outT = (sel == 1) ? Kt2 : Vt2;
        if (sel == 1) {
            #pragma unroll
            for (int ch = 0; ch < 8; ch++) {
                int o = lane * 64 + ch * 8;
                int u = o >> 9, qd = (o >> 7) & 3, l = (o >> 3) & 15;
                int row = (u >> 2) * 32 + ((u >> 1) & 1) * 16 + l;
                int col = (u & 1) * 32 + qd * 8;
                *(bf16x8*)(outT + obase + o) = *(const bf16x8*)&sh.Tl[w][row][col];
            }
        } else {
            #pragma unroll
            for (int ch = 0; ch < 8; ch++) {
                int o = lane * 64 + ch * 8;
                int c = o >> 11, j2 = (o >> 9) & 3, qd = (o >> 7) & 3, l = (o >> 3) & 15;
                int hd = j2 * 16 + l;
                bf16x8 ov;
                #pragma unroll
                for (int jj = 0; jj < 8; jj++) {
                    int s = c * 32 + qd * 8 + jj;
                    // zero-shuffle mapping: key = s-bit-permute {5,2,4,3,1,0}
                    int key = (s & 0x20) | ((s & 0x04) << 2) | ((s & 0x18) >> 1) | (s & 0x03);
                    ov[jj] = sh.Tl[w][key][hd];
                }
                *(bf16x8*)(outT + obase + o) = ov;
            }
        }
    }
}

// ---------------------------------------------------------------------------
// Flash attention, round-13: ZERO-SHUFFLE in-register P.
//   R12 proved in-reg P correct but __shfl = ds_bpermute (DS pipe + lgkm
//   waits) — no gain. Fix: the V-scramble is ours to choose. With
//   phi(c,quad,jj) = 16*(2c+(jj>>2)) + 4*quad + (jj&3) baked into Vt2
//   (see gemm_qkv), the PV A-frag element (lane,jj) for chunk c is exactly
//   exp(z2[m][2c+(jj>>2)][jj&3]) — lane-local. Per (m,c): 4 cvt_pk, zero
//   shuffles, zero selects, zero P DS-ops. Verified: phi is the bijective
//   bit-permute s{5,2,4,3,1,0}->key{5..0}; Lacc row-sum is permutation-
//   invariant; O/merge/epilogue byte-identical to R0/R12.
//   Tripwires: absmax must stay 0.001953125; WRITE_SIZE >> 13 MB = spill.
// ---------------------------------------------------------------------------
__global__ __launch_bounds__(256, 4) void flash_attn(const short* __restrict__ Qb,
                                                     const short* __restrict__ Kt2,
                                                     const short* __restrict__ Vt2,
                                                     short* __restrict__ y) {
    int tid  = threadIdx.x;
    int lane = tid & 63;
    int w    = tid >> 6;
    int quad = lane >> 4;
    int l16  = lane & 15;
    int qsel = w & 1;
    int ksel = w >> 1;

    int bh = blockIdx.y;
    int b  = bh >> 4;
    int h  = bh & 15;
    int qw = blockIdx.x * 64 + qsel * 32;

    __shared__ float Mg[2][64][41];   // merge buffers (20992 B)

    const short* Qrow = Qb + ((long)b * SEQ + qw + l16) * 1024 + h * 64;
    bf16x8 aQ[2][2];
    #pragma unroll
    for (int m = 0; m < 2; m++)
        #pragma unroll
        for (int c = 0; c < 2; c++)
            aQ[m][c] = *(const bf16x8*)(Qrow + (long)(m * 16) * 1024 + c * 32 + quad * 8);

    const short* Ktb = Kt2 + (long)bh * (SEQ * 64) + (long)ksel * 16 * 4096;
    const short* Vtb = Vt2 + (long)bh * (SEQ * 64) + (long)ksel * 16 * 4096;

    f32x4 O[2][4] = {};
    f32x4 Lacc[2] = {};
    bf16x8 ones;
    #pragma unroll
    for (int i = 0; i < 8; i++) ones[i] = (short)0x3F80;   // bf16 1.0

    for (int t = 0; t < 16; t++) {
        const short* Kt = Ktb + t * 4096;
        const short* Vt = Vtb + t * 4096;

        // K fragment loads (coalesced 1KB dwordx4)
        bf16x8 kf[8];
        #pragma unroll
        for (int u = 0; u < 8; u++) kf[u] = *(const bf16x8*)(Kt + u * 512 + lane * 8);

        // S^T = K Q^T (operand-swapped): z2[m][kc][r] at lane (quad,l16)
        // = P[q=qw+16m+l16][key=16kc+4quad+r]
        f32x4 z2[2][4];
        #pragma unroll
        for (int m = 0; m < 2; m++)
            #pragma unroll
            for (int kc = 0; kc < 4; kc++) {
                f32x4 zz = {};
                zz = __builtin_amdgcn_mfma_f32_16x16x32_bf16(kf[2 * kc],     aQ[m][0], zz, 0, 0, 0);
                z2[m][kc] = __builtin_amdgcn_mfma_f32_16x16x32_bf16(kf[2 * kc + 1], aQ[m][1], zz, 0, 0, 0);
            }

        // V fragment loads — consumed right after the lane-local exp/pack
        bf16x8 vf[8];
        #pragma unroll
        for (int u = 0; u < 8; u++) vf[u] = *(const bf16x8*)(Vt + u * 512 + lane * 8);

        // exp + pack DIRECTLY into the A-frag (V pre-scrambled with phi):
        // aP element jj = exp(z2[m][2c+(jj>>2)][jj&3]) — all lane-local.
        #pragma unroll
        for (int m = 0; m < 2; m++)
            #pragma unroll
            for (int c = 0; c < 2; c++) {
                union { unsigned u[4]; bf16x8 v; } cvt;
                cvt.u[0] = pk_bf16(EXP2F(z2[m][2 * c][0]),     EXP2F(z2[m][2 * c][1]));
                cvt.u[1] = pk_bf16(EXP2F(z2[m][2 * c][2]),     EXP2F(z2[m][2 * c][3]));
                cvt.u[2] = pk_bf16(EXP2F(z2[m][2 * c + 1][0]), EXP2F(z2[m][2 * c + 1][1]));
                cvt.u[3] = pk_bf16(EXP2F(z2[m][2 * c + 1][2]), EXP2F(z2[m][2 * c + 1][3]));
                bf16x8 aP = cvt.v;

                Lacc[m] = __builtin_amdgcn_mfma_f32_16x16x32_bf16(aP, ones, Lacc[m], 0, 0, 0);
                #pragma unroll
                for (int j = 0; j < 4; j++)
                    O[m][j] = __builtin_amdgcn_mfma_f32_16x16x32_bf16(aP, vf[c * 4 + j], O[m][j], 0, 0, 0);
            }
    }

    // additive merge of key-split partners (w, w+2)
    __syncthreads();
    if (ksel) {
        float* mg = &Mg[qsel][lane][0];
        #pragma unroll
        for (int m = 0; m < 2; m++)
            #pragma unroll
            for (int j = 0; j < 4; j++)
                #pragma unroll
                for (int r = 0; r < 4; r++)
                    mg[m * 16 + j * 4 + r] = O[m][j][r];
        #pragma unroll
        for (int m = 0; m < 2; m++)
            #pragma unroll
            for (int r = 0; r < 4; r++)
                mg[32 + m * 4 + r] = Lacc[m][r];
    }
    __syncthreads();
    if (!ksel) {
        const float* mg = &Mg[qsel][lane][0];
        #pragma unroll
        for (int m = 0; m < 2; m++)
            #pragma unroll
            for (int j = 0; j < 4; j++)
                #pragma unroll
                for (int r = 0; r < 4; r++)
                    O[m][j][r] += mg[m * 16 + j * 4 + r];
        #pragma unroll
        for (int m = 0; m < 2; m++)
            #pragma unroll
            for (int r = 0; r < 4; r++)
                Lacc[m][r] += mg[32 + m * 4 + r];

        #pragma unroll
        for (int m = 0; m < 2; m++) {
            f32x4 rl;
            #pragma unroll
            for (int r = 0; r < 4; r++) rl[r] = 1.0f / Lacc[m][r];
            #pragma unroll
            for (int j = 0; j < 4; j++)
                #pragma unroll
                for (int r = 0; r < 4; r++) {
                    int row = qw + m * 16 + quad * 4 + r;
                    y[((long)b * SEQ + row) * D_MODEL + h * HD + j * 16 + l16] =
                        f2bf(O[m][j][r] * rl[r]);
                }
        }
    }
}

// ---------------------------------------------------------------------------
// Workspace (48 MB): Qb@0, yb@8M, Kt2@24M, Vt2@32M, WqkvT@40M, WoT@46M.
// x_bf scratched in d_out. repack_kv fused into gemm_qkv.
// ---------------------------------------------------------------------------
extern "C" void kernel_launch(void* const* d_in, const int* in_sizes, int n_in,
                              void* d_out, int out_size, void* d_ws, size_t ws_size,
                              hipStream_t stream) {
    const float* x    = (const float*)d_in[0];
    const float* Wqkv = (const float*)d_in[1];
    const float* Wo   = (const float*)d_in[2];

    char* ws = (char*)d_ws;
    short* Qb    = (short*)(ws);
    short* Kt2   = (short*)(ws + 25165824);
    short* Vt2   = (short*)(ws + 33554432);
    short* WqkvT = (short*)(ws + 41943040);
    short* WoT   = (short*)(ws + 48234496);
    short* x_bf  = (short*)d_out;            // scratch in d_out (16 MB fp32)
    short* yb    = (short*)(ws + 8388608);

    const float cexp = 0.125f * 1.4426950408889634f;  // 1/sqrt(64) * log2(e)

    prep_kernel<<<8192, 256, 0, stream>>>(x, x_bf, Wqkv, WqkvT, Wo, WoT, cexp);

    gemm_qkv<<<dim3(3 * D_MODEL / 128, NTOK / 128), 256, 0, stream>>>(
        x_bf, WqkvT, Qb, Kt2, Vt2);

    flash_attn<<<dim3(SEQ / 64, BATCH * NHEADS), 256, 0, stream>>>(Qb, Kt2, Vt2, yb);

    gemm_out<<<dim3(D_MODEL / 64, NTOK / 128), 256, 0, stream>>>(
        yb, WoT, (float*)d_out, NTOK, D_MODEL, D_MODEL);
}